// Round 2
// baseline (2256.045 us; speedup 1.0000x reference)
//
#include <hip/hip_runtime.h>
#include <stdint.h>

#define PARTITIONABLE 1   // JAX >= 0.4.36 default (jax_threefry_partitionable=True).
                          // Flip to 0 for legacy paired-counter threefry if absmax ~O(1).

#define N_NODES 100000
#define N_EDGES 3200000
#define IN_DIM  512
#define HID     256
#define NCLS    16

// ---------------- Threefry-2x32 (exact JAX schedule) ----------------
__host__ __device__ __forceinline__ uint32_t rotl32(uint32_t v, int d) {
  return (v << d) | (v >> (32 - d));
}

__host__ __device__ __forceinline__ void threefry2x32(uint32_t k0, uint32_t k1,
    uint32_t x0, uint32_t x1, uint32_t& o0, uint32_t& o1) {
  uint32_t ks0 = k0, ks1 = k1, ks2 = k0 ^ k1 ^ 0x1BD11BDAu;
  x0 += ks0; x1 += ks1;
#define TF_R(r) { x0 += x1; x1 = rotl32(x1, r); x1 ^= x0; }
  TF_R(13) TF_R(15) TF_R(26) TF_R(6)
  x0 += ks1; x1 += ks2 + 1u;
  TF_R(17) TF_R(29) TF_R(16) TF_R(24)
  x0 += ks2; x1 += ks0 + 2u;
  TF_R(13) TF_R(15) TF_R(26) TF_R(6)
  x0 += ks0; x1 += ks1 + 3u;
  TF_R(17) TF_R(29) TF_R(16) TF_R(24)
  x0 += ks1; x1 += ks2 + 4u;
  TF_R(13) TF_R(15) TF_R(26) TF_R(6)
  x0 += ks2; x1 += ks0 + 5u;
#undef TF_R
  o0 = x0; o1 = x1;
}

// partitionable 32-bit random bits for flat index (< 2^32 so hi word = 0)
__host__ __device__ __forceinline__ uint32_t tf_bits32(uint32_t k0, uint32_t k1, uint32_t idx) {
  uint32_t o0, o1;
  threefry2x32(k0, k1, 0u, idx, o0, o1);
  return o0 ^ o1;
}

// ---------------- erfinv: XLA/Giles f32 polynomial ----------------
__device__ __forceinline__ float erfinv_f32(float x) {
  float w = -log1pf(-x * x);
  float p;
  if (w < 5.0f) {
    w -= 2.5f;
    p = 2.81022636e-08f;
    p = fmaf(p, w, 3.43273939e-07f);
    p = fmaf(p, w, -3.5233877e-06f);
    p = fmaf(p, w, -4.39150654e-06f);
    p = fmaf(p, w, 0.00021858087f);
    p = fmaf(p, w, -0.00125372503f);
    p = fmaf(p, w, -0.00417768164f);
    p = fmaf(p, w, 0.246640727f);
    p = fmaf(p, w, 1.50140941f);
  } else {
    w = sqrtf(w) - 3.0f;
    p = -0.000200214257f;
    p = fmaf(p, w, 0.000100950558f);
    p = fmaf(p, w, 0.00134934322f);
    p = fmaf(p, w, -0.00367342844f);
    p = fmaf(p, w, 0.00573950773f);
    p = fmaf(p, w, -0.0076224613f);
    p = fmaf(p, w, 0.00943887047f);
    p = fmaf(p, w, 1.00167406f);
    p = fmaf(p, w, 2.83297682f);
  }
  return p * x;
}

// ---------------- small kernels ----------------
__global__ void degrees_k(const int* __restrict__ esrc, const int* __restrict__ edst,
                          int* __restrict__ outd, int* __restrict__ ind) {
  int e = blockIdx.x * blockDim.x + threadIdx.x;  // exact grid = E
  atomicAdd(&outd[esrc[e]], 1);
  atomicAdd(&ind[edst[e]], 1);
}

__global__ void invsqrt_k(const int* __restrict__ outd, const int* __restrict__ ind,
                          float* __restrict__ out_is, float* __restrict__ in_is) {
  int i = blockIdx.x * blockDim.x + threadIdx.x;
  if (i < N_NODES) {
    out_is[i] = rsqrtf(fmaxf((float)outd[i], 1.0f));
    in_is[i]  = rsqrtf(fmaxf((float)ind[i], 1.0f));
  }
}

__global__ void scan_offsets_k(const int* __restrict__ ind, int* __restrict__ row_ofs,
                               int* __restrict__ cursor) {
  __shared__ int part[1024];
  const int tid = threadIdx.x;
  const int chunk = (N_NODES + 1023) / 1024;
  int s0 = tid * chunk;
  int s1 = s0 + chunk; if (s1 > N_NODES) s1 = N_NODES; if (s0 > N_NODES) s0 = N_NODES;
  int sum = 0;
  for (int i = s0; i < s1; ++i) sum += ind[i];
  part[tid] = sum;
  __syncthreads();
  for (int d = 1; d < 1024; d <<= 1) {
    int v = (tid >= d) ? part[tid - d] : 0;
    __syncthreads();
    part[tid] += v;
    __syncthreads();
  }
  int run = part[tid] - sum;  // exclusive prefix of this chunk
  for (int i = s0; i < s1; ++i) {
    row_ofs[i] = run; cursor[i] = run;
    run += ind[i];
  }
  if (tid == 1023) row_ofs[N_NODES] = part[1023];
}

__global__ void scatter_k(const int* __restrict__ esrc, const int* __restrict__ edst,
                          int* __restrict__ cursor, int* __restrict__ csr) {
  int e = blockIdx.x * blockDim.x + threadIdx.x;  // exact grid = E
  int d = edst[e];
  int p = atomicAdd(&cursor[d], 1);
  csr[p] = esrc[e];
}

// ---------------- dropout mask generation (bit arrays, 1 bit per element) ----------------
#if PARTITIONABLE
__global__ void gen_mask_k(uint32_t k0, uint32_t k1, uint32_t* __restrict__ mask) {
  uint32_t idx = blockIdx.x * blockDim.x + threadIdx.x;   // exact grid = size
  uint32_t bits = tf_bits32(k0, k1, idx);
  unsigned long long bal = __ballot((bits >> 31) == 0u);  // keep := u < 0.5
  if ((threadIdx.x & 63) == 0) {
    uint32_t w = idx >> 5;
    mask[w] = (uint32_t)bal;
    mask[w + 1] = (uint32_t)(bal >> 32);
  }
}
#else
__global__ void gen_mask_k(uint32_t k0, uint32_t k1, uint32_t H, uint32_t* __restrict__ mask) {
  uint32_t idx = blockIdx.x * blockDim.x + threadIdx.x;   // exact grid = H
  uint32_t o0, o1;
  threefry2x32(k0, k1, idx, idx + H, o0, o1);
  unsigned long long b0 = __ballot((o0 >> 31) == 0u);
  unsigned long long b1 = __ballot((o1 >> 31) == 0u);
  if ((threadIdx.x & 63) == 0) {
    uint32_t w = idx >> 5;
    mask[w] = (uint32_t)b0; mask[w + 1] = (uint32_t)(b0 >> 32);
    uint32_t w2 = (idx + H) >> 5;
    mask[w2] = (uint32_t)b1; mask[w2 + 1] = (uint32_t)(b1 >> 32);
  }
}
#endif

__device__ __forceinline__ uint32_t eps_bits(uint32_t k0, uint32_t k1, uint32_t i) {
#if PARTITIONABLE
  return tf_bits32(k0, k1, i);
#else
  const uint32_t H = (N_NODES * NCLS) / 2;
  uint32_t o0, o1;
  if (i < H) { threefry2x32(k0, k1, i, i + H, o0, o1); return o0; }
  threefry2x32(k0, k1, i - H, i, o0, o1); return o1;
#endif
}

// ---------------- GEMM1: X1 = (drop1(x)*out_is) @ W1   [100000,512]x[512,256] ----------------
__global__ __launch_bounds__(256) void gemm1_k(
    const float* __restrict__ x, const float* __restrict__ W1,
    const uint32_t* __restrict__ mask1, const float* __restrict__ out_is,
    float* __restrict__ X1) {
  __shared__ float As[32][68];   // k-major, padded
  __shared__ float Bs[32][256];
  const int tid = threadIdx.x;
  const int block_row = blockIdx.x * 64;
  const int tr = (tid >> 5) * 8;
  const int tc = (tid & 31) * 8;
  float acc[8][8];
#pragma unroll
  for (int i = 0; i < 8; ++i)
#pragma unroll
    for (int j = 0; j < 8; ++j) acc[i][j] = 0.0f;

  for (int k0 = 0; k0 < IN_DIM; k0 += 32) {
#pragma unroll
    for (int j = 0; j < 2; ++j) {   // stage A: 64 rows x 32 k, mask+scale, transpose
      int s = j * 256 + tid;
      int row = s >> 3;
      int kl = (s & 7) * 4;
      int grow = block_row + row;
      float4 v = make_float4(0.f, 0.f, 0.f, 0.f);
      if (grow < N_NODES) {
        v = *(const float4*)(x + (size_t)grow * IN_DIM + k0 + kl);
        float sc = 2.0f * out_is[grow];   // /(1-p) * out_inv_sqrt
        uint32_t mw = mask1[((uint32_t)grow * IN_DIM + (uint32_t)(k0 + kl)) >> 5];
        int bp = (k0 + kl) & 31;
        v.x = ((mw >> bp) & 1u)       ? v.x * sc : 0.0f;
        v.y = ((mw >> (bp + 1)) & 1u) ? v.y * sc : 0.0f;
        v.z = ((mw >> (bp + 2)) & 1u) ? v.z * sc : 0.0f;
        v.w = ((mw >> (bp + 3)) & 1u) ? v.w * sc : 0.0f;
      }
      As[kl + 0][row] = v.x;
      As[kl + 1][row] = v.y;
      As[kl + 2][row] = v.z;
      As[kl + 3][row] = v.w;
    }
#pragma unroll
    for (int j = 0; j < 8; ++j) {   // stage B: 32 k x 256 cols
      int s = j * 256 + tid;
      int brow = s >> 6;
      int bcol = (s & 63) * 4;
      *(float4*)&Bs[brow][bcol] = *(const float4*)(W1 + (size_t)(k0 + brow) * HID + bcol);
    }
    __syncthreads();
#pragma unroll 4
    for (int kk = 0; kk < 32; ++kk) {
      float4 a0 = *(const float4*)&As[kk][tr];
      float4 a1 = *(const float4*)&As[kk][tr + 4];
      float4 b0 = *(const float4*)&Bs[kk][tc];
      float4 b1 = *(const float4*)&Bs[kk][tc + 4];
      float av[8] = {a0.x, a0.y, a0.z, a0.w, a1.x, a1.y, a1.z, a1.w};
      float bv[8] = {b0.x, b0.y, b0.z, b0.w, b1.x, b1.y, b1.z, b1.w};
#pragma unroll
      for (int i = 0; i < 8; ++i)
#pragma unroll
        for (int j = 0; j < 8; ++j)
          acc[i][j] = fmaf(av[i], bv[j], acc[i][j]);
    }
    __syncthreads();
  }
#pragma unroll
  for (int i = 0; i < 8; ++i) {
    int grow = block_row + tr + i;
    if (grow < N_NODES) {
      float4 o0 = make_float4(acc[i][0], acc[i][1], acc[i][2], acc[i][3]);
      float4 o1 = make_float4(acc[i][4], acc[i][5], acc[i][6], acc[i][7]);
      *(float4*)(X1 + (size_t)grow * HID + tc) = o0;
      *(float4*)(X1 + (size_t)grow * HID + tc + 4) = o1;
    }
  }
}

// ---------------- CSR gather-sum (256-dim) + relu: h1 = relu(in_is * sum X1[src]) ----------------
__global__ __launch_bounds__(256) void agg_relu_k(
    const float* __restrict__ X1, const int* __restrict__ row_ofs,
    const int* __restrict__ csr, const float* __restrict__ in_is,
    float* __restrict__ h1) {
  int d = blockIdx.x * 4 + (threadIdx.x >> 6);  // exact: 25000*4 = N
  int lane = threadIdx.x & 63;
  int beg = row_ofs[d], end = row_ofs[d + 1];
  float4 s = make_float4(0.f, 0.f, 0.f, 0.f);
  for (int j = beg; j < end; ++j) {
    int src = csr[j];
    float4 v = *(const float4*)(X1 + (size_t)src * HID + lane * 4);
    s.x += v.x; s.y += v.y; s.z += v.z; s.w += v.w;
  }
  float is = in_is[d];
  float4 r;
  r.x = fmaxf(s.x * is, 0.f);
  r.y = fmaxf(s.y * is, 0.f);
  r.z = fmaxf(s.z * is, 0.f);
  r.w = fmaxf(s.w * is, 0.f);
  *(float4*)(h1 + (size_t)d * HID + lane * 4) = r;
}

// ---------------- BatchNorm stats ----------------
__global__ void bn_stats_k(const float* __restrict__ h1, float* __restrict__ bn) {
  int c = threadIdx.x;  // 256 threads
  float s = 0.f, s2 = 0.f;
  for (int r = blockIdx.x; r < N_NODES; r += gridDim.x) {
    float v = h1[(size_t)r * HID + c];
    s += v; s2 += v * v;
  }
  atomicAdd(&bn[c], s);
  atomicAdd(&bn[HID + c], s2);
}

__global__ void bn_fin_k(float* __restrict__ bn) {
  int c = threadIdx.x;
  float mean = bn[c] / (float)N_NODES;
  float var = bn[HID + c] / (float)N_NODES - mean * mean;
  bn[512 + c] = mean;
  bn[768 + c] = rsqrtf(var + 1e-5f);
}

// ---------------- GEMM2/3 fused: X2/X3 = (dropN(BN(h1))*out_is) @ W2/W3 ----------------
__global__ __launch_bounds__(256) void gemm23_k(
    const float* __restrict__ h1, const float* __restrict__ W2,
    const float* __restrict__ W3, const uint32_t* __restrict__ mask2a,
    const uint32_t* __restrict__ mask2b, const float* __restrict__ out_is,
    const float* __restrict__ bn, float* __restrict__ X2, float* __restrict__ X3) {
  __shared__ float Bs[HID][36];   // [k][0..15]=W2 row, [16..31]=W3 row
  __shared__ float At[64][65];    // BN'd, *2*out_is, pre-mask
  __shared__ float Ms[HID];
  __shared__ float Is[HID];
  const int tid = threadIdx.x;
  {
    const float4* w2 = (const float4*)(W2 + (size_t)tid * NCLS);
    const float4* w3 = (const float4*)(W3 + (size_t)tid * NCLS);
#pragma unroll
    for (int q = 0; q < 4; ++q) {
      *(float4*)&Bs[tid][q * 4] = w2[q];
      *(float4*)&Bs[tid][16 + q * 4] = w3[q];
    }
    Ms[tid] = bn[512 + tid];
    Is[tid] = bn[768 + tid];
  }
  const int row = tid & 63;
  const int cg = tid >> 6;              // 0,1 -> X2 ; 2,3 -> X3
  const int brow = blockIdx.x * 64;
  const int grow = brow + row;
  const uint32_t* mk = (cg < 2) ? mask2a : mask2b;
  float acc[8];
#pragma unroll
  for (int j = 0; j < 8; ++j) acc[j] = 0.0f;

  for (int kt = 0; kt < HID; kt += 64) {
    __syncthreads();
#pragma unroll
    for (int j = 0; j < 4; ++j) {
      int s = j * 256 + tid;
      int r = s >> 4;
      int kl = (s & 15) * 4;
      int gr = brow + r;
      float4 v = make_float4(0.f, 0.f, 0.f, 0.f);
      if (gr < N_NODES) {
        v = *(const float4*)(h1 + (size_t)gr * HID + kt + kl);
        float osc = 2.0f * out_is[gr];
        v.x = (v.x - Ms[kt + kl + 0]) * Is[kt + kl + 0] * osc;
        v.y = (v.y - Ms[kt + kl + 1]) * Is[kt + kl + 1] * osc;
        v.z = (v.z - Ms[kt + kl + 2]) * Is[kt + kl + 2] * osc;
        v.w = (v.w - Ms[kt + kl + 3]) * Is[kt + kl + 3] * osc;
      }
      At[r][kl + 0] = v.x; At[r][kl + 1] = v.y;
      At[r][kl + 2] = v.z; At[r][kl + 3] = v.w;
    }
    __syncthreads();
    uint32_t m0 = 0, m1 = 0;
    if (grow < N_NODES) {
      uint32_t base = ((uint32_t)grow * HID + (uint32_t)kt) >> 5;
      m0 = mk[base]; m1 = mk[base + 1];
    }
#pragma unroll 4
    for (int kk = 0; kk < 64; ++kk) {
      uint32_t bit = (kk < 32) ? ((m0 >> kk) & 1u) : ((m1 >> (kk - 32)) & 1u);
      float a = bit ? At[row][kk] : 0.0f;
      float4 b0 = *(const float4*)&Bs[kt + kk][cg * 8];
      float4 b1 = *(const float4*)&Bs[kt + kk][cg * 8 + 4];
      acc[0] = fmaf(a, b0.x, acc[0]);
      acc[1] = fmaf(a, b0.y, acc[1]);
      acc[2] = fmaf(a, b0.z, acc[2]);
      acc[3] = fmaf(a, b0.w, acc[3]);
      acc[4] = fmaf(a, b1.x, acc[4]);
      acc[5] = fmaf(a, b1.y, acc[5]);
      acc[6] = fmaf(a, b1.z, acc[6]);
      acc[7] = fmaf(a, b1.w, acc[7]);
    }
  }
  if (grow < N_NODES) {
    float* dst = (cg < 2) ? X2 : X3;
    int c0 = (cg & 1) * 8;
    float4 o0 = make_float4(acc[0], acc[1], acc[2], acc[3]);
    float4 o1 = make_float4(acc[4], acc[5], acc[6], acc[7]);
    *(float4*)(dst + (size_t)grow * NCLS + c0) = o0;
    *(float4*)(dst + (size_t)grow * NCLS + c0 + 4) = o1;
  }
}

// ---------------- final: aggregate 16-dim mu/logvar + reparameterize ----------------
__global__ __launch_bounds__(256) void agg_final_k(
    const float* __restrict__ X2, const float* __restrict__ X3,
    const int* __restrict__ row_ofs, const int* __restrict__ csr,
    const float* __restrict__ in_is, uint32_t ke0, uint32_t ke1,
    float* __restrict__ out) {
  int g = blockIdx.x * 8 + (threadIdx.x >> 5);  // exact: 12500*8 = N
  int hl = threadIdx.x & 31;
  int dim = hl & 15;
  bool is_mu = hl < 16;
  const float* Xs = is_mu ? X2 : X3;
  int beg = row_ofs[g], end = row_ofs[g + 1];
  float s = 0.f;
  for (int j = beg; j < end; ++j) s += Xs[(size_t)csr[j] * NCLS + dim];
  s *= in_is[g];
  int wl = threadIdx.x & 63;
  float other = __shfl(s, wl ^ 16, 64);  // mu lanes fetch logvar from lane+16
  if (is_mu) {
    uint32_t i = (uint32_t)(g * NCLS + dim);
    uint32_t bits = eps_bits(ke0, ke1, i);
    float f = __uint_as_float((bits >> 9) | 0x3f800000u) - 1.0f;
    const float lo = -0.99999994f;         // nextafter(-1,0)
    float u = fmaxf(lo, fmaf(f, 2.0f, lo)); // (hi-lo) rounds to exactly 2.0f
    float eps = 1.41421356f * erfinv_f32(u);
    out[i] = eps * expf(other) + s;
  }
}

// ---------------- host ----------------
extern "C" void kernel_launch(void* const* d_in, const int* in_sizes, int n_in,
                              void* d_out, int out_size, void* d_ws, size_t ws_size,
                              hipStream_t stream) {
  (void)in_sizes; (void)n_in; (void)out_size; (void)ws_size;
  const float* x  = (const float*)d_in[0];
  const float* W1 = (const float*)d_in[1];
  const float* W2 = (const float*)d_in[2];
  const float* W3 = (const float*)d_in[3];
  const int* esrc = (const int*)d_in[4];
  const int* edst = (const int*)d_in[5];
  float* out = (float*)d_out;

  // derive the 4 subkeys of jax.random.split(jax.random.key(42), 4) on host
  uint32_t kb[8];
#if PARTITIONABLE
  // _threefry_split_foldlike: key_i = FULL threefry output pair at counter (hi=0, lo=i)
  for (int j = 0; j < 4; ++j) {
    threefry2x32(0u, 42u, 0u, (uint32_t)j, kb[2 * j], kb[2 * j + 1]);
  }
#else
  {
    uint32_t a0[4], a1[4];
    for (int i = 0; i < 4; ++i) threefry2x32(0u, 42u, (uint32_t)i, (uint32_t)(i + 4), a0[i], a1[i]);
    kb[0] = a0[0]; kb[1] = a0[1]; kb[2] = a0[2]; kb[3] = a0[3];
    kb[4] = a1[0]; kb[5] = a1[1]; kb[6] = a1[2]; kb[7] = a1[3];
  }
#endif
  // k1=(kb0,kb1) drop-x; k2a=(kb2,kb3); k2b=(kb4,kb5); keps=(kb6,kb7)

  // workspace carve (~246 MB)
  char* p = (char*)d_ws;
  auto take = [&](size_t bytes) -> void* {
    void* r = (void*)p;
    p += (bytes + 255) & ~(size_t)255;
    return r;
  };
  float* X1      = (float*)take(sizeof(float) * (size_t)N_NODES * HID);
  float* h1      = (float*)take(sizeof(float) * (size_t)N_NODES * HID);
  float* X2      = (float*)take(sizeof(float) * (size_t)N_NODES * NCLS);
  float* X3      = (float*)take(sizeof(float) * (size_t)N_NODES * NCLS);
  uint32_t* mask1  = (uint32_t*)take((size_t)N_NODES * IN_DIM / 8);
  uint32_t* mask2a = (uint32_t*)take((size_t)N_NODES * HID / 8);
  uint32_t* mask2b = (uint32_t*)take((size_t)N_NODES * HID / 8);
  int* out_deg   = (int*)take(sizeof(int) * N_NODES);
  int* in_deg    = (int*)take(sizeof(int) * N_NODES);
  float* out_is  = (float*)take(sizeof(float) * N_NODES);
  float* in_is   = (float*)take(sizeof(float) * N_NODES);
  int* row_ofs   = (int*)take(sizeof(int) * (N_NODES + 1));
  int* cursor    = (int*)take(sizeof(int) * N_NODES);
  int* csr       = (int*)take(sizeof(int) * N_EDGES);
  float* bn      = (float*)take(sizeof(float) * 1024);

  hipMemsetAsync(out_deg, 0, sizeof(int) * N_NODES, stream);
  hipMemsetAsync(in_deg, 0, sizeof(int) * N_NODES, stream);
  hipMemsetAsync(bn, 0, sizeof(float) * 512, stream);

  degrees_k<<<N_EDGES / 256, 256, 0, stream>>>(esrc, edst, out_deg, in_deg);
  invsqrt_k<<<(N_NODES + 255) / 256, 256, 0, stream>>>(out_deg, in_deg, out_is, in_is);
  scan_offsets_k<<<1, 1024, 0, stream>>>(in_deg, row_ofs, cursor);
  scatter_k<<<N_EDGES / 256, 256, 0, stream>>>(esrc, edst, cursor, csr);

#if PARTITIONABLE
  gen_mask_k<<<(N_NODES * IN_DIM) / 256, 256, 0, stream>>>(kb[0], kb[1], mask1);
  gen_mask_k<<<(N_NODES * HID) / 256, 256, 0, stream>>>(kb[2], kb[3], mask2a);
  gen_mask_k<<<(N_NODES * HID) / 256, 256, 0, stream>>>(kb[4], kb[5], mask2b);
#else
  gen_mask_k<<<(N_NODES * IN_DIM / 2) / 256, 256, 0, stream>>>(kb[0], kb[1], (uint32_t)(N_NODES * IN_DIM / 2), mask1);
  gen_mask_k<<<(N_NODES * HID / 2) / 256, 256, 0, stream>>>(kb[2], kb[3], (uint32_t)(N_NODES * HID / 2), mask2a);
  gen_mask_k<<<(N_NODES * HID / 2) / 256, 256, 0, stream>>>(kb[4], kb[5], (uint32_t)(N_NODES * HID / 2), mask2b);
#endif

  gemm1_k<<<(N_NODES + 63) / 64, 256, 0, stream>>>(x, W1, mask1, out_is, X1);
  agg_relu_k<<<N_NODES / 4, 256, 0, stream>>>(X1, row_ofs, csr, in_is, h1);
  bn_stats_k<<<512, 256, 0, stream>>>(h1, bn);
  bn_fin_k<<<1, 256, 0, stream>>>(bn);
  gemm23_k<<<(N_NODES + 63) / 64, 256, 0, stream>>>(h1, W2, W3, mask2a, mask2b, out_is, bn, X2, X3);
  agg_final_k<<<N_NODES / 8, 256, 0, stream>>>(X2, X3, row_ofs, csr, in_is, kb[6], kb[7], out);
}

// Round 3
// 1863.924 us; speedup vs baseline: 1.2104x; 1.2104x over previous
//
#include <hip/hip_runtime.h>
#include <stdint.h>

#define N_NODES 100000
#define N_EDGES 3200000
#define IN_DIM  512
#define HID     256
#define NCLS    16

typedef unsigned short u16;
typedef __attribute__((ext_vector_type(8))) short short8;
typedef __attribute__((ext_vector_type(4))) float float4v;

// ---------------- bf16 helpers ----------------
__device__ __forceinline__ float bf2f(u16 u) {
  return __uint_as_float(((uint32_t)u) << 16);
}
__device__ __forceinline__ u16 f2bf(float f) {   // round-to-nearest-even
  uint32_t u = __float_as_uint(f);
  return (u16)((u + 0x7fffu + ((u >> 16) & 1u)) >> 16);
}

// ---------------- Threefry-2x32 (exact JAX schedule, partitionable mode) ----------------
__host__ __device__ __forceinline__ uint32_t rotl32(uint32_t v, int d) {
  return (v << d) | (v >> (32 - d));
}

__host__ __device__ __forceinline__ void threefry2x32(uint32_t k0, uint32_t k1,
    uint32_t x0, uint32_t x1, uint32_t& o0, uint32_t& o1) {
  uint32_t ks0 = k0, ks1 = k1, ks2 = k0 ^ k1 ^ 0x1BD11BDAu;
  x0 += ks0; x1 += ks1;
#define TF_R(r) { x0 += x1; x1 = rotl32(x1, r); x1 ^= x0; }
  TF_R(13) TF_R(15) TF_R(26) TF_R(6)
  x0 += ks1; x1 += ks2 + 1u;
  TF_R(17) TF_R(29) TF_R(16) TF_R(24)
  x0 += ks2; x1 += ks0 + 2u;
  TF_R(13) TF_R(15) TF_R(26) TF_R(6)
  x0 += ks0; x1 += ks1 + 3u;
  TF_R(17) TF_R(29) TF_R(16) TF_R(24)
  x0 += ks1; x1 += ks2 + 4u;
  TF_R(13) TF_R(15) TF_R(26) TF_R(6)
  x0 += ks2; x1 += ks0 + 5u;
#undef TF_R
  o0 = x0; o1 = x1;
}

__host__ __device__ __forceinline__ uint32_t tf_bits32(uint32_t k0, uint32_t k1, uint32_t idx) {
  uint32_t o0, o1;
  threefry2x32(k0, k1, 0u, idx, o0, o1);
  return o0 ^ o1;
}

// ---------------- erfinv: XLA/Giles f32 polynomial ----------------
__device__ __forceinline__ float erfinv_f32(float x) {
  float w = -log1pf(-x * x);
  float p;
  if (w < 5.0f) {
    w -= 2.5f;
    p = 2.81022636e-08f;
    p = fmaf(p, w, 3.43273939e-07f);
    p = fmaf(p, w, -3.5233877e-06f);
    p = fmaf(p, w, -4.39150654e-06f);
    p = fmaf(p, w, 0.00021858087f);
    p = fmaf(p, w, -0.00125372503f);
    p = fmaf(p, w, -0.00417768164f);
    p = fmaf(p, w, 0.246640727f);
    p = fmaf(p, w, 1.50140941f);
  } else {
    w = sqrtf(w) - 3.0f;
    p = -0.000200214257f;
    p = fmaf(p, w, 0.000100950558f);
    p = fmaf(p, w, 0.00134934322f);
    p = fmaf(p, w, -0.00367342844f);
    p = fmaf(p, w, 0.00573950773f);
    p = fmaf(p, w, -0.0076224613f);
    p = fmaf(p, w, 0.00943887047f);
    p = fmaf(p, w, 1.00167406f);
    p = fmaf(p, w, 2.83297682f);
  }
  return p * x;
}

// ---------------- graph prep ----------------
__global__ void degrees_k(const int* __restrict__ esrc, const int* __restrict__ edst,
                          int* __restrict__ outd, int* __restrict__ ind) {
  int e = blockIdx.x * blockDim.x + threadIdx.x;  // exact grid = E
  atomicAdd(&outd[esrc[e]], 1);
  atomicAdd(&ind[edst[e]], 1);
}

__global__ void invsqrt_k(const int* __restrict__ outd, const int* __restrict__ ind,
                          float* __restrict__ out_is, float* __restrict__ in_is) {
  int i = blockIdx.x * blockDim.x + threadIdx.x;
  if (i < N_NODES) {
    out_is[i] = rsqrtf(fmaxf((float)outd[i], 1.0f));
    in_is[i]  = rsqrtf(fmaxf((float)ind[i], 1.0f));
  }
}

__global__ void scan_offsets_k(const int* __restrict__ ind, int* __restrict__ row_ofs,
                               int* __restrict__ cursor) {
  __shared__ int part[1024];
  const int tid = threadIdx.x;
  const int chunk = (N_NODES + 1023) / 1024;
  int s0 = tid * chunk;
  int s1 = s0 + chunk; if (s1 > N_NODES) s1 = N_NODES; if (s0 > N_NODES) s0 = N_NODES;
  int sum = 0;
  for (int i = s0; i < s1; ++i) sum += ind[i];
  part[tid] = sum;
  __syncthreads();
  for (int d = 1; d < 1024; d <<= 1) {
    int v = (tid >= d) ? part[tid - d] : 0;
    __syncthreads();
    part[tid] += v;
    __syncthreads();
  }
  int run = part[tid] - sum;  // exclusive prefix of this chunk
  for (int i = s0; i < s1; ++i) {
    row_ofs[i] = run; cursor[i] = run;
    run += ind[i];
  }
  if (tid == 1023) row_ofs[N_NODES] = part[1023];
}

__global__ void scatter_k(const int* __restrict__ esrc, const int* __restrict__ edst,
                          int* __restrict__ cursor, int* __restrict__ csr) {
  int e = blockIdx.x * blockDim.x + threadIdx.x;  // exact grid = E
  int d = edst[e];
  int p = atomicAdd(&cursor[d], 1);
  csr[p] = esrc[e];
}

// ---------------- dropout mask bits for hidden layer (1 bit per element) ----------------
__global__ void gen_mask_k(uint32_t k0, uint32_t k1, uint32_t* __restrict__ mask) {
  uint32_t idx = blockIdx.x * blockDim.x + threadIdx.x;   // exact grid = size
  uint32_t bits = tf_bits32(k0, k1, idx);
  unsigned long long bal = __ballot((bits >> 31) == 0u);  // keep := u < 0.5
  if ((threadIdx.x & 63) == 0) {
    uint32_t w = idx >> 5;
    mask[w] = (uint32_t)bal;
    mask[w + 1] = (uint32_t)(bal >> 32);
  }
}

// ---------------- Xb = bf16(dropout1(x) * 2 * out_is)  [fuses mask1 threefry] ----------------
__global__ __launch_bounds__(256) void cast_x_k(
    const float* __restrict__ x, const float* __restrict__ out_is,
    uint32_t k0, uint32_t k1, u16* __restrict__ Xb) {
  uint32_t t = blockIdx.x * 256u + threadIdx.x;   // 6.4M threads, 8 elems each
  uint32_t idx = t * 8u;
  uint32_t row = idx >> 9;
  float sc = 2.0f * out_is[row];
  float4 v0 = *(const float4*)(x + idx);
  float4 v1 = *(const float4*)(x + idx + 4);
  float vv[8] = {v0.x, v0.y, v0.z, v0.w, v1.x, v1.y, v1.z, v1.w};
  u16 o[8];
#pragma unroll
  for (int j = 0; j < 8; ++j) {
    uint32_t bits = tf_bits32(k0, k1, idx + (uint32_t)j);
    float val = (bits >> 31) ? 0.0f : vv[j] * sc;
    o[j] = f2bf(val);
  }
  uint4 pk;
  pk.x = (uint32_t)o[0] | ((uint32_t)o[1] << 16);
  pk.y = (uint32_t)o[2] | ((uint32_t)o[3] << 16);
  pk.z = (uint32_t)o[4] | ((uint32_t)o[5] << 16);
  pk.w = (uint32_t)o[6] | ((uint32_t)o[7] << 16);
  *(uint4*)(Xb + idx) = pk;
}

// ---------------- W1t = bf16(W1^T)  [256][512] ----------------
__global__ void cast_w1_k(const float* __restrict__ W1, u16* __restrict__ W1t) {
  int idx = blockIdx.x * blockDim.x + threadIdx.x;   // exact grid = 512*256
  int k = idx >> 8, n = idx & 255;
  W1t[n * IN_DIM + k] = f2bf(W1[idx]);
}

// ---------------- GEMM1 (MFMA bf16): X1b = Xb @ W1  [100000,512]x[512,256] -> bf16 ----------------
// block: 256 thr = 4 waves; tile M=64, N=256. wave w: all 4 row-tiles x col-tiles [4w,4w+4)
#define LDA 40   // ushort stride (80 B: 16B-aligned rows, dword-stride 20 -> <=2-way bank alias)
__global__ __launch_bounds__(256) void gemm1_k(
    const u16* __restrict__ Xb, const u16* __restrict__ W1t, u16* __restrict__ X1b) {
  __shared__ u16 As[64 * LDA];    // [row][k0..31]
  __shared__ u16 Bs[256 * LDA];   // [n][k0..31]
  const int tid = threadIdx.x;
  const int w = tid >> 6, l = tid & 63;
  const int m16 = l & 15, q = l >> 4;
  const long base_row = (long)blockIdx.x * 64;

  float4v acc[4][4];
#pragma unroll
  for (int i = 0; i < 4; ++i)
#pragma unroll
    for (int j = 0; j < 4; ++j) acc[i][j] = (float4v)0.0f;

  const int arow = tid >> 2, ac = tid & 3;   // A staging: 64 rows x 4 chunks(8 bf16)
  const long agr = base_row + arow;

  for (int k0 = 0; k0 < IN_DIM; k0 += 32) {
    uint4 va = make_uint4(0, 0, 0, 0);
    if (agr < N_NODES) va = *(const uint4*)(Xb + agr * IN_DIM + k0 + ac * 8);
    *(uint4*)(As + arow * LDA + ac * 8) = va;
#pragma unroll
    for (int c = 0; c < 4; ++c) {   // B staging: n = tid, 32 bf16 per row (L2-resident W1t)
      uint4 vb = *(const uint4*)(W1t + (size_t)tid * IN_DIM + k0 + c * 8);
      *(uint4*)(Bs + tid * LDA + c * 8) = vb;
    }
    __syncthreads();
    short8 a[4], b[4];
#pragma unroll
    for (int rt = 0; rt < 4; ++rt)
      a[rt] = *(const short8*)(As + (rt * 16 + m16) * LDA + q * 8);
#pragma unroll
    for (int ct = 0; ct < 4; ++ct)
      b[ct] = *(const short8*)(Bs + ((w * 4 + ct) * 16 + m16) * LDA + q * 8);
#pragma unroll
    for (int rt = 0; rt < 4; ++rt)
#pragma unroll
      for (int ct = 0; ct < 4; ++ct)
        acc[rt][ct] = __builtin_amdgcn_mfma_f32_16x16x32_bf16(a[rt], b[ct], acc[rt][ct], 0, 0, 0);
    __syncthreads();
  }
  // epilogue: D row=(q*4+r), col=m16 within each 16x16 tile
#pragma unroll
  for (int rt = 0; rt < 4; ++rt) {
#pragma unroll
    for (int r = 0; r < 4; ++r) {
      long grow = base_row + rt * 16 + q * 4 + r;
      if (grow < N_NODES) {
#pragma unroll
        for (int ct = 0; ct < 4; ++ct)
          X1b[grow * HID + (w * 4 + ct) * 16 + m16] = f2bf(acc[rt][ct][r]);
      }
    }
  }
}

// ---------------- CSR gather-sum (bf16) + relu -> h1 bf16 ----------------
__global__ __launch_bounds__(256) void agg_relu_k(
    const u16* __restrict__ X1b, const int* __restrict__ row_ofs,
    const int* __restrict__ csr, const float* __restrict__ in_is,
    u16* __restrict__ h1b) {
  int d = blockIdx.x * 4 + (threadIdx.x >> 6);  // exact: 25000*4 = N
  int lane = threadIdx.x & 63;
  int beg = row_ofs[d], end = row_ofs[d + 1];
  float s0 = 0.f, s1 = 0.f, s2 = 0.f, s3 = 0.f;
  for (int j = beg; j < end; ++j) {
    int src = csr[j];
    uint2 v = *(const uint2*)(X1b + (size_t)src * HID + lane * 4);
    s0 += bf2f((u16)(v.x & 0xffffu));
    s1 += bf2f((u16)(v.x >> 16));
    s2 += bf2f((u16)(v.y & 0xffffu));
    s3 += bf2f((u16)(v.y >> 16));
  }
  float is = in_is[d];
  u16 r0 = f2bf(fmaxf(s0 * is, 0.f));
  u16 r1 = f2bf(fmaxf(s1 * is, 0.f));
  u16 r2 = f2bf(fmaxf(s2 * is, 0.f));
  u16 r3 = f2bf(fmaxf(s3 * is, 0.f));
  uint2 pk;
  pk.x = (uint32_t)r0 | ((uint32_t)r1 << 16);
  pk.y = (uint32_t)r2 | ((uint32_t)r3 << 16);
  *(uint2*)(h1b + (size_t)d * HID + lane * 4) = pk;
}

// ---------------- BatchNorm stats (bf16 in, fp32 accumulate) ----------------
__global__ void bn_stats_k(const u16* __restrict__ h1b, float* __restrict__ bn) {
  int c = threadIdx.x;  // 256 threads
  float s = 0.f, s2 = 0.f;
  for (int r = blockIdx.x; r < N_NODES; r += gridDim.x) {
    float v = bf2f(h1b[(size_t)r * HID + c]);
    s += v; s2 += v * v;
  }
  atomicAdd(&bn[c], s);
  atomicAdd(&bn[HID + c], s2);
}

__global__ void bn_fin_k(float* __restrict__ bn) {
  int c = threadIdx.x;
  float mean = bn[c] / (float)N_NODES;
  float var = bn[HID + c] / (float)N_NODES - mean * mean;
  bn[512 + c] = mean;
  bn[768 + c] = rsqrtf(var + 1e-5f);
}

// ---------------- GEMM2/3 fused: X2/X3 = (dropN(BN(h1))*out_is) @ W2/W3 -> bf16 ----------------
__global__ __launch_bounds__(256) void gemm23_k(
    const u16* __restrict__ h1b, const float* __restrict__ W2,
    const float* __restrict__ W3, const uint32_t* __restrict__ mask2a,
    const uint32_t* __restrict__ mask2b, const float* __restrict__ out_is,
    const float* __restrict__ bn, u16* __restrict__ X2b, u16* __restrict__ X3b) {
  __shared__ float Bs[HID][36];   // [k][0..15]=W2 row, [16..31]=W3 row
  __shared__ float At[64][65];    // BN'd, *2*out_is, pre-mask
  __shared__ float Ms[HID];
  __shared__ float Is[HID];
  const int tid = threadIdx.x;
  {
    const float4* w2 = (const float4*)(W2 + (size_t)tid * NCLS);
    const float4* w3 = (const float4*)(W3 + (size_t)tid * NCLS);
#pragma unroll
    for (int q = 0; q < 4; ++q) {
      *(float4*)&Bs[tid][q * 4] = w2[q];
      *(float4*)&Bs[tid][16 + q * 4] = w3[q];
    }
    Ms[tid] = bn[512 + tid];
    Is[tid] = bn[768 + tid];
  }
  const int row = tid & 63;
  const int cg = tid >> 6;              // 0,1 -> X2 ; 2,3 -> X3
  const int brow = blockIdx.x * 64;
  const int grow = brow + row;
  const uint32_t* mk = (cg < 2) ? mask2a : mask2b;
  float acc[8];
#pragma unroll
  for (int j = 0; j < 8; ++j) acc[j] = 0.0f;

  for (int kt = 0; kt < HID; kt += 64) {
    __syncthreads();
#pragma unroll
    for (int j = 0; j < 4; ++j) {
      int s = j * 256 + tid;
      int r = s >> 4;
      int kl = (s & 15) * 4;
      int gr = brow + r;
      float4 v = make_float4(0.f, 0.f, 0.f, 0.f);
      if (gr < N_NODES) {
        uint2 hv = *(const uint2*)(h1b + (size_t)gr * HID + kt + kl);
        float osc = 2.0f * out_is[gr];
        v.x = (bf2f((u16)(hv.x & 0xffffu)) - Ms[kt + kl + 0]) * Is[kt + kl + 0] * osc;
        v.y = (bf2f((u16)(hv.x >> 16))     - Ms[kt + kl + 1]) * Is[kt + kl + 1] * osc;
        v.z = (bf2f((u16)(hv.y & 0xffffu)) - Ms[kt + kl + 2]) * Is[kt + kl + 2] * osc;
        v.w = (bf2f((u16)(hv.y >> 16))     - Ms[kt + kl + 3]) * Is[kt + kl + 3] * osc;
      }
      At[r][kl + 0] = v.x; At[r][kl + 1] = v.y;
      At[r][kl + 2] = v.z; At[r][kl + 3] = v.w;
    }
    __syncthreads();
    uint32_t m0 = 0, m1 = 0;
    if (grow < N_NODES) {
      uint32_t base = ((uint32_t)grow * HID + (uint32_t)kt) >> 5;
      m0 = mk[base]; m1 = mk[base + 1];
    }
#pragma unroll 4
    for (int kk = 0; kk < 64; ++kk) {
      uint32_t bit = (kk < 32) ? ((m0 >> kk) & 1u) : ((m1 >> (kk - 32)) & 1u);
      float a = bit ? At[row][kk] : 0.0f;
      float4 b0 = *(const float4*)&Bs[kt + kk][cg * 8];
      float4 b1 = *(const float4*)&Bs[kt + kk][cg * 8 + 4];
      acc[0] = fmaf(a, b0.x, acc[0]);
      acc[1] = fmaf(a, b0.y, acc[1]);
      acc[2] = fmaf(a, b0.z, acc[2]);
      acc[3] = fmaf(a, b0.w, acc[3]);
      acc[4] = fmaf(a, b1.x, acc[4]);
      acc[5] = fmaf(a, b1.y, acc[5]);
      acc[6] = fmaf(a, b1.z, acc[6]);
      acc[7] = fmaf(a, b1.w, acc[7]);
    }
  }
  if (grow < N_NODES) {
    u16* dst = (cg < 2) ? X2b : X3b;
    int c0 = (cg & 1) * 8;
    uint4 pk;
    pk.x = (uint32_t)f2bf(acc[0]) | ((uint32_t)f2bf(acc[1]) << 16);
    pk.y = (uint32_t)f2bf(acc[2]) | ((uint32_t)f2bf(acc[3]) << 16);
    pk.z = (uint32_t)f2bf(acc[4]) | ((uint32_t)f2bf(acc[5]) << 16);
    pk.w = (uint32_t)f2bf(acc[6]) | ((uint32_t)f2bf(acc[7]) << 16);
    *(uint4*)(dst + (size_t)grow * NCLS + c0) = pk;
  }
}

// ---------------- final: aggregate 16-dim mu/logvar (bf16) + reparameterize ----------------
__global__ __launch_bounds__(256) void agg_final_k(
    const u16* __restrict__ X2b, const u16* __restrict__ X3b,
    const int* __restrict__ row_ofs, const int* __restrict__ csr,
    const float* __restrict__ in_is, uint32_t ke0, uint32_t ke1,
    float* __restrict__ out) {
  int g = blockIdx.x * 8 + (threadIdx.x >> 5);  // exact: 12500*8 = N
  int hl = threadIdx.x & 31;
  int dim = hl & 15;
  bool is_mu = hl < 16;
  const u16* Xs = is_mu ? X2b : X3b;
  int beg = row_ofs[g], end = row_ofs[g + 1];
  float s = 0.f;
  for (int j = beg; j < end; ++j) s += bf2f(Xs[(size_t)csr[j] * NCLS + dim]);
  s *= in_is[g];
  int wl = threadIdx.x & 63;
  float other = __shfl(s, wl ^ 16, 64);  // mu lanes fetch logvar from lane+16
  if (is_mu) {
    uint32_t i = (uint32_t)(g * NCLS + dim);
    uint32_t bits = tf_bits32(ke0, ke1, i);
    float f = __uint_as_float((bits >> 9) | 0x3f800000u) - 1.0f;
    const float lo = -0.99999994f;          // nextafter(-1,0)
    float u = fmaxf(lo, fmaf(f, 2.0f, lo)); // (hi-lo) rounds to exactly 2.0f
    float eps = 1.41421356f * erfinv_f32(u);
    out[i] = eps * expf(other) + s;
  }
}

// ---------------- host ----------------
extern "C" void kernel_launch(void* const* d_in, const int* in_sizes, int n_in,
                              void* d_out, int out_size, void* d_ws, size_t ws_size,
                              hipStream_t stream) {
  (void)in_sizes; (void)n_in; (void)out_size; (void)ws_size;
  const float* x  = (const float*)d_in[0];
  const float* W1 = (const float*)d_in[1];
  const float* W2 = (const float*)d_in[2];
  const float* W3 = (const float*)d_in[3];
  const int* esrc = (const int*)d_in[4];
  const int* edst = (const int*)d_in[5];
  float* out = (float*)d_out;

  // subkeys of jax.random.split(jax.random.key(42), 4):
  // partitionable split -> key_i = FULL threefry output pair at counter (hi=0, lo=i)
  uint32_t kb[8];
  for (int j = 0; j < 4; ++j)
    threefry2x32(0u, 42u, 0u, (uint32_t)j, kb[2 * j], kb[2 * j + 1]);
  // k1=(kb0,kb1) drop-x; k2a=(kb2,kb3); k2b=(kb4,kb5); keps=(kb6,kb7)

  // workspace carve (~233 MB; R2 used 244 MB successfully)
  char* p = (char*)d_ws;
  auto take = [&](size_t bytes) -> void* {
    void* r = (void*)p;
    p += (bytes + 255) & ~(size_t)255;
    return r;
  };
  u16* Xb        = (u16*)take(sizeof(u16) * (size_t)N_NODES * IN_DIM);
  u16* X1b       = (u16*)take(sizeof(u16) * (size_t)N_NODES * HID);
  u16* h1b       = (u16*)take(sizeof(u16) * (size_t)N_NODES * HID);
  u16* X2b       = (u16*)take(sizeof(u16) * (size_t)N_NODES * NCLS);
  u16* X3b       = (u16*)take(sizeof(u16) * (size_t)N_NODES * NCLS);
  u16* W1t       = (u16*)take(sizeof(u16) * (size_t)IN_DIM * HID);
  uint32_t* mask2a = (uint32_t*)take((size_t)N_NODES * HID / 8);
  uint32_t* mask2b = (uint32_t*)take((size_t)N_NODES * HID / 8);
  int* out_deg   = (int*)take(sizeof(int) * N_NODES);
  int* in_deg    = (int*)take(sizeof(int) * N_NODES);
  float* out_is  = (float*)take(sizeof(float) * N_NODES);
  float* in_is   = (float*)take(sizeof(float) * N_NODES);
  int* row_ofs   = (int*)take(sizeof(int) * (N_NODES + 1));
  int* cursor    = (int*)take(sizeof(int) * N_NODES);
  int* csr       = (int*)take(sizeof(int) * N_EDGES);
  float* bn      = (float*)take(sizeof(float) * 1024);

  hipMemsetAsync(out_deg, 0, sizeof(int) * N_NODES, stream);
  hipMemsetAsync(in_deg, 0, sizeof(int) * N_NODES, stream);
  hipMemsetAsync(bn, 0, sizeof(float) * 512, stream);

  degrees_k<<<N_EDGES / 256, 256, 0, stream>>>(esrc, edst, out_deg, in_deg);
  invsqrt_k<<<(N_NODES + 255) / 256, 256, 0, stream>>>(out_deg, in_deg, out_is, in_is);
  scan_offsets_k<<<1, 1024, 0, stream>>>(in_deg, row_ofs, cursor);
  scatter_k<<<N_EDGES / 256, 256, 0, stream>>>(esrc, edst, cursor, csr);

  gen_mask_k<<<(N_NODES * HID) / 256, 256, 0, stream>>>(kb[2], kb[3], mask2a);
  gen_mask_k<<<(N_NODES * HID) / 256, 256, 0, stream>>>(kb[4], kb[5], mask2b);

  cast_w1_k<<<(IN_DIM * HID) / 256, 256, 0, stream>>>(W1, W1t);
  cast_x_k<<<(N_NODES * IN_DIM / 8) / 256, 256, 0, stream>>>(x, out_is, kb[0], kb[1], Xb);

  gemm1_k<<<(N_NODES + 63) / 64, 256, 0, stream>>>(Xb, W1t, X1b);
  agg_relu_k<<<N_NODES / 4, 256, 0, stream>>>(X1b, row_ofs, csr, in_is, h1b);
  bn_stats_k<<<512, 256, 0, stream>>>(h1b, bn);
  bn_fin_k<<<1, 256, 0, stream>>>(bn);
  gemm23_k<<<(N_NODES + 63) / 64, 256, 0, stream>>>(h1b, W2, W3, mask2a, mask2b, out_is, bn, X2b, X3b);
  agg_final_k<<<N_NODES / 8, 256, 0, stream>>>(X2b, X3b, row_ofs, csr, in_is, kb[6], kb[7], out);
}

// Round 4
// 1624.456 us; speedup vs baseline: 1.3888x; 1.1474x over previous
//
#include <hip/hip_runtime.h>
#include <stdint.h>

#define N_NODES 100000
#define N_EDGES 3200000
#define IN_DIM  512
#define HID     256
#define NCLS    16

typedef unsigned short u16;
typedef __attribute__((ext_vector_type(8))) short short8;
typedef __attribute__((ext_vector_type(4))) float float4v;

// ---------------- bf16 helpers ----------------
__device__ __forceinline__ float bf2f(u16 u) {
  return __uint_as_float(((uint32_t)u) << 16);
}
__device__ __forceinline__ u16 f2bf(float f) {   // round-to-nearest-even
  uint32_t u = __float_as_uint(f);
  return (u16)((u + 0x7fffu + ((u >> 16) & 1u)) >> 16);
}
__device__ __forceinline__ void acc8(float* a, uint4 v) {
  a[0] += bf2f((u16)(v.x & 0xffffu)); a[1] += bf2f((u16)(v.x >> 16));
  a[2] += bf2f((u16)(v.y & 0xffffu)); a[3] += bf2f((u16)(v.y >> 16));
  a[4] += bf2f((u16)(v.z & 0xffffu)); a[5] += bf2f((u16)(v.z >> 16));
  a[6] += bf2f((u16)(v.w & 0xffffu)); a[7] += bf2f((u16)(v.w >> 16));
}

// ---------------- Threefry-2x32 (exact JAX schedule, partitionable mode) ----------------
__host__ __device__ __forceinline__ uint32_t rotl32(uint32_t v, int d) {
  return (v << d) | (v >> (32 - d));
}

__host__ __device__ __forceinline__ void threefry2x32(uint32_t k0, uint32_t k1,
    uint32_t x0, uint32_t x1, uint32_t& o0, uint32_t& o1) {
  uint32_t ks0 = k0, ks1 = k1, ks2 = k0 ^ k1 ^ 0x1BD11BDAu;
  x0 += ks0; x1 += ks1;
#define TF_R(r) { x0 += x1; x1 = rotl32(x1, r); x1 ^= x0; }
  TF_R(13) TF_R(15) TF_R(26) TF_R(6)
  x0 += ks1; x1 += ks2 + 1u;
  TF_R(17) TF_R(29) TF_R(16) TF_R(24)
  x0 += ks2; x1 += ks0 + 2u;
  TF_R(13) TF_R(15) TF_R(26) TF_R(6)
  x0 += ks0; x1 += ks1 + 3u;
  TF_R(17) TF_R(29) TF_R(16) TF_R(24)
  x0 += ks1; x1 += ks2 + 4u;
  TF_R(13) TF_R(15) TF_R(26) TF_R(6)
  x0 += ks2; x1 += ks0 + 5u;
#undef TF_R
  o0 = x0; o1 = x1;
}

__host__ __device__ __forceinline__ uint32_t tf_bits32(uint32_t k0, uint32_t k1, uint32_t idx) {
  uint32_t o0, o1;
  threefry2x32(k0, k1, 0u, idx, o0, o1);
  return o0 ^ o1;
}

// ---------------- erfinv: XLA/Giles f32 polynomial ----------------
__device__ __forceinline__ float erfinv_f32(float x) {
  float w = -log1pf(-x * x);
  float p;
  if (w < 5.0f) {
    w -= 2.5f;
    p = 2.81022636e-08f;
    p = fmaf(p, w, 3.43273939e-07f);
    p = fmaf(p, w, -3.5233877e-06f);
    p = fmaf(p, w, -4.39150654e-06f);
    p = fmaf(p, w, 0.00021858087f);
    p = fmaf(p, w, -0.00125372503f);
    p = fmaf(p, w, -0.00417768164f);
    p = fmaf(p, w, 0.246640727f);
    p = fmaf(p, w, 1.50140941f);
  } else {
    w = sqrtf(w) - 3.0f;
    p = -0.000200214257f;
    p = fmaf(p, w, 0.000100950558f);
    p = fmaf(p, w, 0.00134934322f);
    p = fmaf(p, w, -0.00367342844f);
    p = fmaf(p, w, 0.00573950773f);
    p = fmaf(p, w, -0.0076224613f);
    p = fmaf(p, w, 0.00943887047f);
    p = fmaf(p, w, 1.00167406f);
    p = fmaf(p, w, 2.83297682f);
  }
  return p * x;
}

// ---------------- graph prep ----------------
__global__ void degrees_k(const int* __restrict__ esrc, const int* __restrict__ edst,
                          int* __restrict__ outd, int* __restrict__ ind) {
  int e = blockIdx.x * blockDim.x + threadIdx.x;  // exact grid = E
  atomicAdd(&outd[esrc[e]], 1);
  atomicAdd(&ind[edst[e]], 1);
}

__global__ void invsqrt_k(const int* __restrict__ outd, const int* __restrict__ ind,
                          float* __restrict__ out_is, float* __restrict__ in_is) {
  int i = blockIdx.x * blockDim.x + threadIdx.x;
  if (i < N_NODES) {
    out_is[i] = rsqrtf(fmaxf((float)outd[i], 1.0f));
    in_is[i]  = rsqrtf(fmaxf((float)ind[i], 1.0f));
  }
}

__global__ void scan_offsets_k(const int* __restrict__ ind, int* __restrict__ row_ofs,
                               int* __restrict__ cursor) {
  __shared__ int part[1024];
  const int tid = threadIdx.x;
  const int chunk = (N_NODES + 1023) / 1024;
  int s0 = tid * chunk;
  int s1 = s0 + chunk; if (s1 > N_NODES) s1 = N_NODES; if (s0 > N_NODES) s0 = N_NODES;
  int sum = 0;
  for (int i = s0; i < s1; ++i) sum += ind[i];
  part[tid] = sum;
  __syncthreads();
  for (int d = 1; d < 1024; d <<= 1) {
    int v = (tid >= d) ? part[tid - d] : 0;
    __syncthreads();
    part[tid] += v;
    __syncthreads();
  }
  int run = part[tid] - sum;  // exclusive prefix of this chunk
  for (int i = s0; i < s1; ++i) {
    row_ofs[i] = run; cursor[i] = run;
    run += ind[i];
  }
  if (tid == 1023) row_ofs[N_NODES] = part[1023];
}

__global__ void scatter_k(const int* __restrict__ esrc, const int* __restrict__ edst,
                          int* __restrict__ cursor, int* __restrict__ csr) {
  int e = blockIdx.x * blockDim.x + threadIdx.x;  // exact grid = E
  int d = edst[e];
  int p = atomicAdd(&cursor[d], 1);
  csr[p] = esrc[e];
}

// ---------------- dropout mask bits for hidden layer (1 bit per element) ----------------
__global__ void gen_mask_k(uint32_t k0, uint32_t k1, uint32_t* __restrict__ mask) {
  uint32_t idx = blockIdx.x * blockDim.x + threadIdx.x;   // exact grid = size
  uint32_t bits = tf_bits32(k0, k1, idx);
  unsigned long long bal = __ballot((bits >> 31) == 0u);  // keep := u < 0.5
  if ((threadIdx.x & 63) == 0) {
    uint32_t w = idx >> 5;
    mask[w] = (uint32_t)bal;
    mask[w + 1] = (uint32_t)(bal >> 32);
  }
}

// ---------------- Xb = bf16(dropout1(x) * 2 * out_is) ----------------
__global__ __launch_bounds__(256) void cast_x_k(
    const float* __restrict__ x, const float* __restrict__ out_is,
    uint32_t k0, uint32_t k1, u16* __restrict__ Xb) {
  uint32_t t = blockIdx.x * 256u + threadIdx.x;   // 6.4M threads, 8 elems each
  uint32_t idx = t * 8u;
  uint32_t row = idx >> 9;
  float sc = 2.0f * out_is[row];
  float4 v0 = *(const float4*)(x + idx);
  float4 v1 = *(const float4*)(x + idx + 4);
  float vv[8] = {v0.x, v0.y, v0.z, v0.w, v1.x, v1.y, v1.z, v1.w};
  u16 o[8];
#pragma unroll
  for (int j = 0; j < 8; ++j) {
    uint32_t bits = tf_bits32(k0, k1, idx + (uint32_t)j);
    float val = (bits >> 31) ? 0.0f : vv[j] * sc;
    o[j] = f2bf(val);
  }
  uint4 pk;
  pk.x = (uint32_t)o[0] | ((uint32_t)o[1] << 16);
  pk.y = (uint32_t)o[2] | ((uint32_t)o[3] << 16);
  pk.z = (uint32_t)o[4] | ((uint32_t)o[5] << 16);
  pk.w = (uint32_t)o[6] | ((uint32_t)o[7] << 16);
  *(uint4*)(Xb + idx) = pk;
}

// ---------------- W1t = bf16(W1^T)  [256][512] ----------------
__global__ void cast_w1_k(const float* __restrict__ W1, u16* __restrict__ W1t) {
  int idx = blockIdx.x * blockDim.x + threadIdx.x;   // exact grid = 512*256
  int k = idx >> 8, n = idx & 255;
  W1t[n * IN_DIM + k] = f2bf(W1[idx]);
}

// ---------------- Wt23 = bf16([W2^T ; W3^T])  [32][256] ----------------
__global__ void cast_w23_k(const float* __restrict__ W2, const float* __restrict__ W3,
                           u16* __restrict__ Wt23) {
  int idx = blockIdx.x * blockDim.x + threadIdx.x;   // exact grid = 32*256
  int n = idx >> 8, k = idx & 255;
  float v = (n < 16) ? W2[k * NCLS + n] : W3[k * NCLS + (n - 16)];
  Wt23[n * HID + k] = f2bf(v);
}

// ---------------- GEMM1 (MFMA bf16): X1b = Xb @ W1  [100000,512]x[512,256] -> bf16 ----------------
#define LDA 40   // ushort stride (80 B: 16B-aligned rows, dword-stride 20 -> <=2-way bank alias)
__global__ __launch_bounds__(256) void gemm1_k(
    const u16* __restrict__ Xb, const u16* __restrict__ W1t, u16* __restrict__ X1b) {
  __shared__ u16 As[64 * LDA];    // [row][k0..31]
  __shared__ u16 Bs[256 * LDA];   // [n][k0..31]
  const int tid = threadIdx.x;
  const int w = tid >> 6, l = tid & 63;
  const int m16 = l & 15, q = l >> 4;
  const long base_row = (long)blockIdx.x * 64;

  float4v acc[4][4];
#pragma unroll
  for (int i = 0; i < 4; ++i)
#pragma unroll
    for (int j = 0; j < 4; ++j) acc[i][j] = (float4v)0.0f;

  const int arow = tid >> 2, ac = tid & 3;   // A staging: 64 rows x 4 chunks(8 bf16)
  const long agr = base_row + arow;

  for (int k0 = 0; k0 < IN_DIM; k0 += 32) {
    uint4 va = make_uint4(0, 0, 0, 0);
    if (agr < N_NODES) va = *(const uint4*)(Xb + agr * IN_DIM + k0 + ac * 8);
    *(uint4*)(As + arow * LDA + ac * 8) = va;
#pragma unroll
    for (int c = 0; c < 4; ++c) {   // B staging: n = tid, 32 bf16 per row (L2-resident W1t)
      uint4 vb = *(const uint4*)(W1t + (size_t)tid * IN_DIM + k0 + c * 8);
      *(uint4*)(Bs + tid * LDA + c * 8) = vb;
    }
    __syncthreads();
    short8 a[4], b[4];
#pragma unroll
    for (int rt = 0; rt < 4; ++rt)
      a[rt] = *(const short8*)(As + (rt * 16 + m16) * LDA + q * 8);
#pragma unroll
    for (int ct = 0; ct < 4; ++ct)
      b[ct] = *(const short8*)(Bs + ((w * 4 + ct) * 16 + m16) * LDA + q * 8);
#pragma unroll
    for (int rt = 0; rt < 4; ++rt)
#pragma unroll
      for (int ct = 0; ct < 4; ++ct)
        acc[rt][ct] = __builtin_amdgcn_mfma_f32_16x16x32_bf16(a[rt], b[ct], acc[rt][ct], 0, 0, 0);
    __syncthreads();
  }
#pragma unroll
  for (int rt = 0; rt < 4; ++rt) {
#pragma unroll
    for (int r = 0; r < 4; ++r) {
      long grow = base_row + rt * 16 + q * 4 + r;
      if (grow < N_NODES) {
#pragma unroll
        for (int ct = 0; ct < 4; ++ct)
          X1b[grow * HID + (w * 4 + ct) * 16 + m16] = f2bf(acc[rt][ct][r]);
      }
    }
  }
}

// ---------------- CSR gather-sum (bf16) + relu -> h1 bf16 ----------------
// wave per node; two half-waves process alternate edges (full 512B row per half-wave,
// uint4 per lane); 2-deep unroll -> 4 independent row loads in flight.
__global__ __launch_bounds__(256) void agg_relu_k(
    const u16* __restrict__ X1b, const int* __restrict__ row_ofs,
    const int* __restrict__ csr, const float* __restrict__ in_is,
    u16* __restrict__ h1b) {
  int d = blockIdx.x * 4 + (threadIdx.x >> 6);  // exact: 25000*4 = N
  int lane = threadIdx.x & 63;
  int half = lane >> 5;
  int col = (lane & 31) * 8;
  int beg = row_ofs[d], end = row_ofs[d + 1];
  float a[8];
#pragma unroll
  for (int i = 0; i < 8; ++i) a[i] = 0.0f;
  int j = beg + half;
  for (; j + 2 < end; j += 4) {
    int s0 = csr[j], s1 = csr[j + 2];
    uint4 v0 = *(const uint4*)(X1b + (size_t)s0 * HID + col);
    uint4 v1 = *(const uint4*)(X1b + (size_t)s1 * HID + col);
    acc8(a, v0);
    acc8(a, v1);
  }
  for (; j < end; j += 2) {
    uint4 v0 = *(const uint4*)(X1b + (size_t)csr[j] * HID + col);
    acc8(a, v0);
  }
#pragma unroll
  for (int i = 0; i < 8; ++i) a[i] += __shfl(a[i], lane ^ 32, 64);
  if (half == 0) {
    float is = in_is[d];
    u16 o[8];
#pragma unroll
    for (int i = 0; i < 8; ++i) o[i] = f2bf(fmaxf(a[i] * is, 0.0f));
    uint4 pk;
    pk.x = (uint32_t)o[0] | ((uint32_t)o[1] << 16);
    pk.y = (uint32_t)o[2] | ((uint32_t)o[3] << 16);
    pk.z = (uint32_t)o[4] | ((uint32_t)o[5] << 16);
    pk.w = (uint32_t)o[6] | ((uint32_t)o[7] << 16);
    *(uint4*)(h1b + (size_t)d * HID + col) = pk;
  }
}

// ---------------- BatchNorm stats (bf16 in, fp32 accumulate) ----------------
__global__ void bn_stats_k(const u16* __restrict__ h1b, float* __restrict__ bn) {
  int c = threadIdx.x;  // 256 threads
  float s = 0.f, s2 = 0.f;
  for (int r = blockIdx.x; r < N_NODES; r += gridDim.x) {
    float v = bf2f(h1b[(size_t)r * HID + c]);
    s += v; s2 += v * v;
  }
  atomicAdd(&bn[c], s);
  atomicAdd(&bn[HID + c], s2);
}

__global__ void bn_fin_k(float* __restrict__ bn) {
  int c = threadIdx.x;
  float mean = bn[c] / (float)N_NODES;
  float var = bn[HID + c] / (float)N_NODES - mean * mean;
  float istd = rsqrtf(var + 1e-5f);
  bn[512 + c] = istd;           // cB
  bn[768 + c] = -mean * istd;   // cA:  normalized = h*cB + cA
}

// ---------------- GEMM2/3 (MFMA): XMLV[row] = [mu(16) | logvar(16)] bf16 ----------------
// A built in registers from h1b (BN + dropout masks + 2*out_is), two masked variants,
// two 16x16x32 MFMAs per k-chunk. Block = 64 rows (4 waves x 16).
#define WLS 264   // u16 row stride for Wls: dword-stride 132 -> 2-way bank alias (free)
__global__ __launch_bounds__(256) void gemm23_k(
    const u16* __restrict__ h1b, const u16* __restrict__ Wt23,
    const uint32_t* __restrict__ mask2a, const uint32_t* __restrict__ mask2b,
    const float* __restrict__ out_is, const float* __restrict__ bn,
    u16* __restrict__ XMLV) {
  __shared__ u16 Wls[32 * WLS];
  __shared__ float cB[HID], cA[HID];
  const int tid = threadIdx.x;
#pragma unroll
  for (int i = 0; i < 4; ++i) {   // stage Wt23 (16KB) into padded LDS
    int idx = tid + i * 256;      // 1024 uint4 chunks
    int n = idx >> 5, c = idx & 31;
    *(uint4*)(Wls + n * WLS + c * 8) = ((const uint4*)Wt23)[idx];
  }
  cB[tid] = bn[512 + tid];
  cA[tid] = bn[768 + tid];
  __syncthreads();

  const int wv = tid >> 6, lane = tid & 63;
  const int m = lane & 15, q = lane >> 4;
  const long arow = (long)blockIdx.x * 64 + wv * 16 + m;   // A row this lane loads
  const bool valid = arow < N_NODES;
  const float osc = valid ? 2.0f * out_is[arow] : 0.0f;

  float4v accM = (float4v)0.0f, accL = (float4v)0.0f;
  for (int kc = 0; kc < HID; kc += 32) {
    const int kof = kc + q * 8;
    uint4 hv = make_uint4(0, 0, 0, 0);
    uint32_t wa = 0, wb = 0;
    if (valid) {
      hv = *(const uint4*)(h1b + arow * HID + kof);
      uint32_t widx = ((uint32_t)arow * HID + (uint32_t)kc) >> 5;
      wa = mask2a[widx] >> (q * 8);
      wb = mask2b[widx] >> (q * 8);
    }
    float4 B0 = *(const float4*)(cB + kof);
    float4 B1 = *(const float4*)(cB + kof + 4);
    float4 A0 = *(const float4*)(cA + kof);
    float4 A1 = *(const float4*)(cA + kof + 4);
    float hval[8] = {
      bf2f((u16)(hv.x & 0xffffu)), bf2f((u16)(hv.x >> 16)),
      bf2f((u16)(hv.y & 0xffffu)), bf2f((u16)(hv.y >> 16)),
      bf2f((u16)(hv.z & 0xffffu)), bf2f((u16)(hv.z >> 16)),
      bf2f((u16)(hv.w & 0xffffu)), bf2f((u16)(hv.w >> 16))};
    float nb[8] = {B0.x, B0.y, B0.z, B0.w, B1.x, B1.y, B1.z, B1.w};
    float na[8] = {A0.x, A0.y, A0.z, A0.w, A1.x, A1.y, A1.z, A1.w};
    short8 Aa, Ab;
#pragma unroll
    for (int jj = 0; jj < 8; ++jj) {
      float t = fmaf(hval[jj], nb[jj], na[jj]) * osc;
      u16 tb = f2bf(t);
      Aa[jj] = (short)(((wa >> jj) & 1u) ? tb : 0);
      Ab[jj] = (short)(((wb >> jj) & 1u) ? tb : 0);
    }
    short8 Bm = *(const short8*)(Wls + m * WLS + kof);          // W2 col m
    short8 Bl = *(const short8*)(Wls + (16 + m) * WLS + kof);   // W3 col m
    accM = __builtin_amdgcn_mfma_f32_16x16x32_bf16(Aa, Bm, accM, 0, 0, 0);
    accL = __builtin_amdgcn_mfma_f32_16x16x32_bf16(Ab, Bl, accL, 0, 0, 0);
  }
  // D: row = q*4+r, col = m
#pragma unroll
  for (int r = 0; r < 4; ++r) {
    long srow = (long)blockIdx.x * 64 + wv * 16 + q * 4 + r;
    if (srow < N_NODES) {
      XMLV[srow * 32 + m]      = f2bf(accM[r]);
      XMLV[srow * 32 + 16 + m] = f2bf(accL[r]);
    }
  }
}

// ---------------- final: aggregate interleaved mu|logvar + reparameterize ----------------
// wave per node; per edge 32 lanes read one 64B XMLV row; halves = alternate edges.
__global__ __launch_bounds__(256) void agg_final_k(
    const u16* __restrict__ XMLV, const int* __restrict__ row_ofs,
    const int* __restrict__ csr, const float* __restrict__ in_is,
    uint32_t ke0, uint32_t ke1, float* __restrict__ out) {
  int g = blockIdx.x * 4 + (threadIdx.x >> 6);  // exact: 25000*4 = N
  int lane = threadIdx.x & 63;
  int half = lane >> 5, c = lane & 31;
  int beg = row_ofs[g], end = row_ofs[g + 1];
  float s = 0.f;
  int j = beg + half;
  for (; j + 2 < end; j += 4) {
    int s0 = csr[j], s1 = csr[j + 2];
    float v0 = bf2f(XMLV[(size_t)s0 * 32 + c]);
    float v1 = bf2f(XMLV[(size_t)s1 * 32 + c]);
    s += v0; s += v1;
  }
  for (; j < end; j += 2) s += bf2f(XMLV[(size_t)csr[j] * 32 + c]);
  s += __shfl(s, lane ^ 32, 64);
  if (half == 0) {
    s *= in_is[g];
    float other = __shfl(s, lane ^ 16, 64);  // mu lane c gets logvar from lane c+16
    if (c < 16) {
      uint32_t i = (uint32_t)(g * NCLS + c);
      uint32_t bits = tf_bits32(ke0, ke1, i);
      float f = __uint_as_float((bits >> 9) | 0x3f800000u) - 1.0f;
      const float lo = -0.99999994f;          // nextafter(-1,0)
      float u = fmaxf(lo, fmaf(f, 2.0f, lo)); // (hi-lo) rounds to exactly 2.0f
      float eps = 1.41421356f * erfinv_f32(u);
      out[i] = eps * expf(other) + s;
    }
  }
}

// ---------------- host ----------------
extern "C" void kernel_launch(void* const* d_in, const int* in_sizes, int n_in,
                              void* d_out, int out_size, void* d_ws, size_t ws_size,
                              hipStream_t stream) {
  (void)in_sizes; (void)n_in; (void)out_size; (void)ws_size;
  const float* x  = (const float*)d_in[0];
  const float* W1 = (const float*)d_in[1];
  const float* W2 = (const float*)d_in[2];
  const float* W3 = (const float*)d_in[3];
  const int* esrc = (const int*)d_in[4];
  const int* edst = (const int*)d_in[5];
  float* out = (float*)d_out;

  // subkeys of jax.random.split(jax.random.key(42), 4):
  // partitionable split -> key_i = FULL threefry output pair at counter (hi=0, lo=i)
  uint32_t kb[8];
  for (int j = 0; j < 4; ++j)
    threefry2x32(0u, 42u, 0u, (uint32_t)j, kb[2 * j], kb[2 * j + 1]);
  // k1=(kb0,kb1) drop-x; k2a=(kb2,kb3); k2b=(kb4,kb5); keps=(kb6,kb7)

  // workspace carve
  char* p = (char*)d_ws;
  auto take = [&](size_t bytes) -> void* {
    void* r = (void*)p;
    p += (bytes + 255) & ~(size_t)255;
    return r;
  };
  u16* Xb        = (u16*)take(sizeof(u16) * (size_t)N_NODES * IN_DIM);
  u16* X1b       = (u16*)take(sizeof(u16) * (size_t)N_NODES * HID);
  u16* h1b       = (u16*)take(sizeof(u16) * (size_t)N_NODES * HID);
  u16* XMLV      = (u16*)take(sizeof(u16) * (size_t)N_NODES * 32);
  u16* W1t       = (u16*)take(sizeof(u16) * (size_t)IN_DIM * HID);
  u16* Wt23      = (u16*)take(sizeof(u16) * 32 * HID);
  uint32_t* mask2a = (uint32_t*)take((size_t)N_NODES * HID / 8);
  uint32_t* mask2b = (uint32_t*)take((size_t)N_NODES * HID / 8);
  int* out_deg   = (int*)take(sizeof(int) * N_NODES);
  int* in_deg    = (int*)take(sizeof(int) * N_NODES);
  float* out_is  = (float*)take(sizeof(float) * N_NODES);
  float* in_is   = (float*)take(sizeof(float) * N_NODES);
  int* row_ofs   = (int*)take(sizeof(int) * (N_NODES + 1));
  int* cursor    = (int*)take(sizeof(int) * N_NODES);
  int* csr       = (int*)take(sizeof(int) * N_EDGES);
  float* bn      = (float*)take(sizeof(float) * 1024);

  hipMemsetAsync(out_deg, 0, sizeof(int) * N_NODES, stream);
  hipMemsetAsync(in_deg, 0, sizeof(int) * N_NODES, stream);
  hipMemsetAsync(bn, 0, sizeof(float) * 512, stream);

  degrees_k<<<N_EDGES / 256, 256, 0, stream>>>(esrc, edst, out_deg, in_deg);
  invsqrt_k<<<(N_NODES + 255) / 256, 256, 0, stream>>>(out_deg, in_deg, out_is, in_is);
  scan_offsets_k<<<1, 1024, 0, stream>>>(in_deg, row_ofs, cursor);
  scatter_k<<<N_EDGES / 256, 256, 0, stream>>>(esrc, edst, cursor, csr);

  gen_mask_k<<<(N_NODES * HID) / 256, 256, 0, stream>>>(kb[2], kb[3], mask2a);
  gen_mask_k<<<(N_NODES * HID) / 256, 256, 0, stream>>>(kb[4], kb[5], mask2b);

  cast_w1_k<<<(IN_DIM * HID) / 256, 256, 0, stream>>>(W1, W1t);
  cast_w23_k<<<(32 * HID) / 256, 256, 0, stream>>>(W2, W3, Wt23);
  cast_x_k<<<(N_NODES * IN_DIM / 8) / 256, 256, 0, stream>>>(x, out_is, kb[0], kb[1], Xb);

  gemm1_k<<<(N_NODES + 63) / 64, 256, 0, stream>>>(Xb, W1t, X1b);
  agg_relu_k<<<N_NODES / 4, 256, 0, stream>>>(X1b, row_ofs, csr, in_is, h1b);
  bn_stats_k<<<512, 256, 0, stream>>>(h1b, bn);
  bn_fin_k<<<1, 256, 0, stream>>>(bn);
  gemm23_k<<<(N_NODES + 63) / 64, 256, 0, stream>>>(h1b, Wt23, mask2a, mask2b, out_is, bn, XMLV);
  agg_final_k<<<N_NODES / 4, 256, 0, stream>>>(XMLV, row_ofs, csr, in_is, kb[6], kb[7], out);
}

// Round 5
// 1540.227 us; speedup vs baseline: 1.4647x; 1.0547x over previous
//
#include <hip/hip_runtime.h>
#include <stdint.h>

#define N_NODES 100000
#define N_EDGES 3200000
#define IN_DIM  512
#define HID     256
#define NCLS    16
#define NPASS   8        // dst-window passes for the CSR scatter
#define WINSZ   (N_NODES / NPASS)   // 12500

typedef unsigned short u16;
typedef __attribute__((ext_vector_type(8))) short short8;
typedef __attribute__((ext_vector_type(4))) float float4v;

// ---------------- bf16 helpers ----------------
__device__ __forceinline__ float bf2f(u16 u) {
  return __uint_as_float(((uint32_t)u) << 16);
}
__device__ __forceinline__ u16 f2bf(float f) {   // round-to-nearest-even
  uint32_t u = __float_as_uint(f);
  return (u16)((u + 0x7fffu + ((u >> 16) & 1u)) >> 16);
}
__device__ __forceinline__ void acc8(float* a, uint4 v) {
  a[0] += bf2f((u16)(v.x & 0xffffu)); a[1] += bf2f((u16)(v.x >> 16));
  a[2] += bf2f((u16)(v.y & 0xffffu)); a[3] += bf2f((u16)(v.y >> 16));
  a[4] += bf2f((u16)(v.z & 0xffffu)); a[5] += bf2f((u16)(v.z >> 16));
  a[6] += bf2f((u16)(v.w & 0xffffu)); a[7] += bf2f((u16)(v.w >> 16));
}

// ---------------- Threefry-2x32 (exact JAX schedule, partitionable mode) ----------------
__host__ __device__ __forceinline__ uint32_t rotl32(uint32_t v, int d) {
  return (v << d) | (v >> (32 - d));
}

__host__ __device__ __forceinline__ void threefry2x32(uint32_t k0, uint32_t k1,
    uint32_t x0, uint32_t x1, uint32_t& o0, uint32_t& o1) {
  uint32_t ks0 = k0, ks1 = k1, ks2 = k0 ^ k1 ^ 0x1BD11BDAu;
  x0 += ks0; x1 += ks1;
#define TF_R(r) { x0 += x1; x1 = rotl32(x1, r); x1 ^= x0; }
  TF_R(13) TF_R(15) TF_R(26) TF_R(6)
  x0 += ks1; x1 += ks2 + 1u;
  TF_R(17) TF_R(29) TF_R(16) TF_R(24)
  x0 += ks2; x1 += ks0 + 2u;
  TF_R(13) TF_R(15) TF_R(26) TF_R(6)
  x0 += ks0; x1 += ks1 + 3u;
  TF_R(17) TF_R(29) TF_R(16) TF_R(24)
  x0 += ks1; x1 += ks2 + 4u;
  TF_R(13) TF_R(15) TF_R(26) TF_R(6)
  x0 += ks2; x1 += ks0 + 5u;
#undef TF_R
  o0 = x0; o1 = x1;
}

__host__ __device__ __forceinline__ uint32_t tf_bits32(uint32_t k0, uint32_t k1, uint32_t idx) {
  uint32_t o0, o1;
  threefry2x32(k0, k1, 0u, idx, o0, o1);
  return o0 ^ o1;
}

// ---------------- erfinv: XLA/Giles f32 polynomial ----------------
__device__ __forceinline__ float erfinv_f32(float x) {
  float w = -log1pf(-x * x);
  float p;
  if (w < 5.0f) {
    w -= 2.5f;
    p = 2.81022636e-08f;
    p = fmaf(p, w, 3.43273939e-07f);
    p = fmaf(p, w, -3.5233877e-06f);
    p = fmaf(p, w, -4.39150654e-06f);
    p = fmaf(p, w, 0.00021858087f);
    p = fmaf(p, w, -0.00125372503f);
    p = fmaf(p, w, -0.00417768164f);
    p = fmaf(p, w, 0.246640727f);
    p = fmaf(p, w, 1.50140941f);
  } else {
    w = sqrtf(w) - 3.0f;
    p = -0.000200214257f;
    p = fmaf(p, w, 0.000100950558f);
    p = fmaf(p, w, 0.00134934322f);
    p = fmaf(p, w, -0.00367342844f);
    p = fmaf(p, w, 0.00573950773f);
    p = fmaf(p, w, -0.0076224613f);
    p = fmaf(p, w, 0.00943887047f);
    p = fmaf(p, w, 1.00167406f);
    p = fmaf(p, w, 2.83297682f);
  }
  return p * x;
}

// ---------------- graph prep ----------------
__global__ void degrees_k(const int* __restrict__ esrc, const int* __restrict__ edst,
                          int* __restrict__ outd, int* __restrict__ ind) {
  int e = blockIdx.x * blockDim.x + threadIdx.x;  // exact grid = E
  atomicAdd(&outd[esrc[e]], 1);
  atomicAdd(&ind[edst[e]], 1);
}

__global__ void invsqrt_k(const int* __restrict__ outd, const int* __restrict__ ind,
                          float* __restrict__ out_is, float* __restrict__ in_is) {
  int i = blockIdx.x * blockDim.x + threadIdx.x;
  if (i < N_NODES) {
    out_is[i] = rsqrtf(fmaxf((float)outd[i], 1.0f));
    in_is[i]  = rsqrtf(fmaxf((float)ind[i], 1.0f));
  }
}

__global__ void scan_offsets_k(const int* __restrict__ ind, int* __restrict__ row_ofs,
                               int* __restrict__ cursor) {
  __shared__ int part[1024];
  const int tid = threadIdx.x;
  const int chunk = (N_NODES + 1023) / 1024;
  int s0 = tid * chunk;
  int s1 = s0 + chunk; if (s1 > N_NODES) s1 = N_NODES; if (s0 > N_NODES) s0 = N_NODES;
  int sum = 0;
  for (int i = s0; i < s1; ++i) sum += ind[i];
  part[tid] = sum;
  __syncthreads();
  for (int d = 1; d < 1024; d <<= 1) {
    int v = (tid >= d) ? part[tid - d] : 0;
    __syncthreads();
    part[tid] += v;
    __syncthreads();
  }
  int run = part[tid] - sum;  // exclusive prefix of this chunk
  for (int i = s0; i < s1; ++i) {
    row_ofs[i] = run; cursor[i] = run;
    run += ind[i];
  }
  if (tid == 1023) row_ofs[N_NODES] = part[1023];
}

// windowed scatter: only edges with dst in [lo, lo+WINSZ) are placed this pass.
// csr/cursor window is L2-resident -> each csr line written back once (no 15x amp).
__global__ __launch_bounds__(256) void scatter_win_k(
    const int* __restrict__ esrc, const int* __restrict__ edst,
    int* __restrict__ cursor, int* __restrict__ csr, int lo) {
  int e = blockIdx.x * 256 + threadIdx.x;  // exact grid = E
  int d = edst[e];
  if ((unsigned)(d - lo) < (unsigned)WINSZ) {
    int p = atomicAdd(&cursor[d], 1);
    csr[p] = esrc[e];
  }
}

// ---------------- dropout mask bits for hidden layer (1 bit per element) ----------------
__global__ void gen_mask_k(uint32_t k0, uint32_t k1, uint32_t* __restrict__ mask) {
  uint32_t idx = blockIdx.x * blockDim.x + threadIdx.x;   // exact grid = size
  uint32_t bits = tf_bits32(k0, k1, idx);
  unsigned long long bal = __ballot((bits >> 31) == 0u);  // keep := u < 0.5
  if ((threadIdx.x & 63) == 0) {
    uint32_t w = idx >> 5;
    mask[w] = (uint32_t)bal;
    mask[w + 1] = (uint32_t)(bal >> 32);
  }
}

// ---------------- Xb = bf16(dropout1(x) * 2 * out_is) ----------------
__global__ __launch_bounds__(256) void cast_x_k(
    const float* __restrict__ x, const float* __restrict__ out_is,
    uint32_t k0, uint32_t k1, u16* __restrict__ Xb) {
  uint32_t t = blockIdx.x * 256u + threadIdx.x;   // 6.4M threads, 8 elems each
  uint32_t idx = t * 8u;
  uint32_t row = idx >> 9;
  float sc = 2.0f * out_is[row];
  float4 v0 = *(const float4*)(x + idx);
  float4 v1 = *(const float4*)(x + idx + 4);
  float vv[8] = {v0.x, v0.y, v0.z, v0.w, v1.x, v1.y, v1.z, v1.w};
  u16 o[8];
#pragma unroll
  for (int j = 0; j < 8; ++j) {
    uint32_t bits = tf_bits32(k0, k1, idx + (uint32_t)j);
    float val = (bits >> 31) ? 0.0f : vv[j] * sc;
    o[j] = f2bf(val);
  }
  uint4 pk;
  pk.x = (uint32_t)o[0] | ((uint32_t)o[1] << 16);
  pk.y = (uint32_t)o[2] | ((uint32_t)o[3] << 16);
  pk.z = (uint32_t)o[4] | ((uint32_t)o[5] << 16);
  pk.w = (uint32_t)o[6] | ((uint32_t)o[7] << 16);
  *(uint4*)(Xb + idx) = pk;
}

// ---------------- W1t = bf16(W1^T)  [256][512] ----------------
__global__ void cast_w1_k(const float* __restrict__ W1, u16* __restrict__ W1t) {
  int idx = blockIdx.x * blockDim.x + threadIdx.x;   // exact grid = 512*256
  int k = idx >> 8, n = idx & 255;
  W1t[n * IN_DIM + k] = f2bf(W1[idx]);
}

// ---------------- Wt23 = bf16([W2^T ; W3^T])  [32][256] ----------------
__global__ void cast_w23_k(const float* __restrict__ W2, const float* __restrict__ W3,
                           u16* __restrict__ Wt23) {
  int idx = blockIdx.x * blockDim.x + threadIdx.x;   // exact grid = 32*256
  int n = idx >> 8, k = idx & 255;
  float v = (n < 16) ? W2[k * NCLS + n] : W3[k * NCLS + (n - 16)];
  Wt23[n * HID + k] = f2bf(v);
}

// ---------------- GEMM1 (MFMA bf16): X1b = Xb @ W1  [100000,512]x[512,256] -> bf16 ----------------
#define LDA 40   // ushort stride (80 B: 16B-aligned rows, dword-stride 20 -> <=2-way bank alias)
__global__ __launch_bounds__(256) void gemm1_k(
    const u16* __restrict__ Xb, const u16* __restrict__ W1t, u16* __restrict__ X1b) {
  __shared__ u16 As[64 * LDA];    // [row][k0..31]
  __shared__ u16 Bs[256 * LDA];   // [n][k0..31]
  const int tid = threadIdx.x;
  const int w = tid >> 6, l = tid & 63;
  const int m16 = l & 15, q = l >> 4;
  const long base_row = (long)blockIdx.x * 64;

  float4v acc[4][4];
#pragma unroll
  for (int i = 0; i < 4; ++i)
#pragma unroll
    for (int j = 0; j < 4; ++j) acc[i][j] = (float4v)0.0f;

  const int arow = tid >> 2, ac = tid & 3;   // A staging: 64 rows x 4 chunks(8 bf16)
  const long agr = base_row + arow;

  for (int k0 = 0; k0 < IN_DIM; k0 += 32) {
    uint4 va = make_uint4(0, 0, 0, 0);
    if (agr < N_NODES) va = *(const uint4*)(Xb + agr * IN_DIM + k0 + ac * 8);
    *(uint4*)(As + arow * LDA + ac * 8) = va;
#pragma unroll
    for (int c = 0; c < 4; ++c) {   // B staging: n = tid, 32 bf16 per row (L2-resident W1t)
      uint4 vb = *(const uint4*)(W1t + (size_t)tid * IN_DIM + k0 + c * 8);
      *(uint4*)(Bs + tid * LDA + c * 8) = vb;
    }
    __syncthreads();
    short8 a[4], b[4];
#pragma unroll
    for (int rt = 0; rt < 4; ++rt)
      a[rt] = *(const short8*)(As + (rt * 16 + m16) * LDA + q * 8);
#pragma unroll
    for (int ct = 0; ct < 4; ++ct)
      b[ct] = *(const short8*)(Bs + ((w * 4 + ct) * 16 + m16) * LDA + q * 8);
#pragma unroll
    for (int rt = 0; rt < 4; ++rt)
#pragma unroll
      for (int ct = 0; ct < 4; ++ct)
        acc[rt][ct] = __builtin_amdgcn_mfma_f32_16x16x32_bf16(a[rt], b[ct], acc[rt][ct], 0, 0, 0);
    __syncthreads();
  }
#pragma unroll
  for (int rt = 0; rt < 4; ++rt) {
#pragma unroll
    for (int r = 0; r < 4; ++r) {
      long grow = base_row + rt * 16 + q * 4 + r;
      if (grow < N_NODES) {
#pragma unroll
        for (int ct = 0; ct < 4; ++ct)
          X1b[grow * HID + (w * 4 + ct) * 16 + m16] = f2bf(acc[rt][ct][r]);
      }
    }
  }
}

// ---------------- CSR gather-sum (bf16) + relu -> h1 bf16 ----------------
// wave per node; two half-waves process alternate edges (full 512B row per half-wave,
// uint4 per lane); 4-deep unroll -> 8 independent row loads in flight per wave.
__global__ __launch_bounds__(256) void agg_relu_k(
    const u16* __restrict__ X1b, const int* __restrict__ row_ofs,
    const int* __restrict__ csr, const float* __restrict__ in_is,
    u16* __restrict__ h1b) {
  int d = blockIdx.x * 4 + (threadIdx.x >> 6);  // exact: 25000*4 = N
  int lane = threadIdx.x & 63;
  int half = lane >> 5;
  int col = (lane & 31) * 8;
  int beg = row_ofs[d], end = row_ofs[d + 1];
  float a[8];
#pragma unroll
  for (int i = 0; i < 8; ++i) a[i] = 0.0f;
  int j = beg + half;
  for (; j + 6 < end; j += 8) {
    int s0 = csr[j], s1 = csr[j + 2], s2 = csr[j + 4], s3 = csr[j + 6];
    uint4 v0 = *(const uint4*)(X1b + (size_t)s0 * HID + col);
    uint4 v1 = *(const uint4*)(X1b + (size_t)s1 * HID + col);
    uint4 v2 = *(const uint4*)(X1b + (size_t)s2 * HID + col);
    uint4 v3 = *(const uint4*)(X1b + (size_t)s3 * HID + col);
    acc8(a, v0); acc8(a, v1); acc8(a, v2); acc8(a, v3);
  }
  for (; j < end; j += 2) {
    uint4 v0 = *(const uint4*)(X1b + (size_t)csr[j] * HID + col);
    acc8(a, v0);
  }
#pragma unroll
  for (int i = 0; i < 8; ++i) a[i] += __shfl(a[i], lane ^ 32, 64);
  if (half == 0) {
    float is = in_is[d];
    u16 o[8];
#pragma unroll
    for (int i = 0; i < 8; ++i) o[i] = f2bf(fmaxf(a[i] * is, 0.0f));
    uint4 pk;
    pk.x = (uint32_t)o[0] | ((uint32_t)o[1] << 16);
    pk.y = (uint32_t)o[2] | ((uint32_t)o[3] << 16);
    pk.z = (uint32_t)o[4] | ((uint32_t)o[5] << 16);
    pk.w = (uint32_t)o[6] | ((uint32_t)o[7] << 16);
    *(uint4*)(h1b + (size_t)d * HID + col) = pk;
  }
}

// ---------------- BatchNorm stats (bf16 in, fp32 accumulate) ----------------
__global__ void bn_stats_k(const u16* __restrict__ h1b, float* __restrict__ bn) {
  int c = threadIdx.x;  // 256 threads
  float s = 0.f, s2 = 0.f;
  for (int r = blockIdx.x; r < N_NODES; r += gridDim.x) {
    float v = bf2f(h1b[(size_t)r * HID + c]);
    s += v; s2 += v * v;
  }
  atomicAdd(&bn[c], s);
  atomicAdd(&bn[HID + c], s2);
}

__global__ void bn_fin_k(float* __restrict__ bn) {
  int c = threadIdx.x;
  float mean = bn[c] / (float)N_NODES;
  float var = bn[HID + c] / (float)N_NODES - mean * mean;
  float istd = rsqrtf(var + 1e-5f);
  bn[512 + c] = istd;           // cB
  bn[768 + c] = -mean * istd;   // cA:  normalized = h*cB + cA
}

// ---------------- GEMM2/3 (MFMA): XMLV[row] = [mu(16) | logvar(16)] bf16 ----------------
#define WLS 264   // u16 row stride for Wls: dword-stride 132 -> 2-way bank alias (free)
__global__ __launch_bounds__(256) void gemm23_k(
    const u16* __restrict__ h1b, const u16* __restrict__ Wt23,
    const uint32_t* __restrict__ mask2a, const uint32_t* __restrict__ mask2b,
    const float* __restrict__ out_is, const float* __restrict__ bn,
    u16* __restrict__ XMLV) {
  __shared__ u16 Wls[32 * WLS];
  __shared__ float cB[HID], cA[HID];
  const int tid = threadIdx.x;
#pragma unroll
  for (int i = 0; i < 4; ++i) {   // stage Wt23 (16KB) into padded LDS
    int idx = tid + i * 256;      // 1024 uint4 chunks
    int n = idx >> 5, c = idx & 31;
    *(uint4*)(Wls + n * WLS + c * 8) = ((const uint4*)Wt23)[idx];
  }
  cB[tid] = bn[512 + tid];
  cA[tid] = bn[768 + tid];
  __syncthreads();

  const int wv = tid >> 6, lane = tid & 63;
  const int m = lane & 15, q = lane >> 4;
  const long arow = (long)blockIdx.x * 64 + wv * 16 + m;   // A row this lane loads
  const bool valid = arow < N_NODES;
  const float osc = valid ? 2.0f * out_is[arow] : 0.0f;

  float4v accM = (float4v)0.0f, accL = (float4v)0.0f;
  for (int kc = 0; kc < HID; kc += 32) {
    const int kof = kc + q * 8;
    uint4 hv = make_uint4(0, 0, 0, 0);
    uint32_t wa = 0, wb = 0;
    if (valid) {
      hv = *(const uint4*)(h1b + arow * HID + kof);
      uint32_t widx = ((uint32_t)arow * HID + (uint32_t)kc) >> 5;
      wa = mask2a[widx] >> (q * 8);
      wb = mask2b[widx] >> (q * 8);
    }
    float4 B0 = *(const float4*)(cB + kof);
    float4 B1 = *(const float4*)(cB + kof + 4);
    float4 A0 = *(const float4*)(cA + kof);
    float4 A1 = *(const float4*)(cA + kof + 4);
    float hval[8] = {
      bf2f((u16)(hv.x & 0xffffu)), bf2f((u16)(hv.x >> 16)),
      bf2f((u16)(hv.y & 0xffffu)), bf2f((u16)(hv.y >> 16)),
      bf2f((u16)(hv.z & 0xffffu)), bf2f((u16)(hv.z >> 16)),
      bf2f((u16)(hv.w & 0xffffu)), bf2f((u16)(hv.w >> 16))};
    float nb[8] = {B0.x, B0.y, B0.z, B0.w, B1.x, B1.y, B1.z, B1.w};
    float na[8] = {A0.x, A0.y, A0.z, A0.w, A1.x, A1.y, A1.z, A1.w};
    short8 Aa, Ab;
#pragma unroll
    for (int jj = 0; jj < 8; ++jj) {
      float t = fmaf(hval[jj], nb[jj], na[jj]) * osc;
      u16 tb = f2bf(t);
      Aa[jj] = (short)(((wa >> jj) & 1u) ? tb : 0);
      Ab[jj] = (short)(((wb >> jj) & 1u) ? tb : 0);
    }
    short8 Bm = *(const short8*)(Wls + m * WLS + kof);          // W2 col m
    short8 Bl = *(const short8*)(Wls + (16 + m) * WLS + kof);   // W3 col m
    accM = __builtin_amdgcn_mfma_f32_16x16x32_bf16(Aa, Bm, accM, 0, 0, 0);
    accL = __builtin_amdgcn_mfma_f32_16x16x32_bf16(Ab, Bl, accL, 0, 0, 0);
  }
  // D: row = q*4+r, col = m
#pragma unroll
  for (int r = 0; r < 4; ++r) {
    long srow = (long)blockIdx.x * 64 + wv * 16 + q * 4 + r;
    if (srow < N_NODES) {
      XMLV[srow * 32 + m]      = f2bf(accM[r]);
      XMLV[srow * 32 + 16 + m] = f2bf(accL[r]);
    }
  }
}

// ---------------- final: aggregate interleaved mu|logvar + reparameterize ----------------
__global__ __launch_bounds__(256) void agg_final_k(
    const u16* __restrict__ XMLV, const int* __restrict__ row_ofs,
    const int* __restrict__ csr, const float* __restrict__ in_is,
    uint32_t ke0, uint32_t ke1, float* __restrict__ out) {
  int g = blockIdx.x * 4 + (threadIdx.x >> 6);  // exact: 25000*4 = N
  int lane = threadIdx.x & 63;
  int half = lane >> 5, c = lane & 31;
  int beg = row_ofs[g], end = row_ofs[g + 1];
  float s = 0.f;
  int j = beg + half;
  for (; j + 6 < end; j += 8) {
    int s0 = csr[j], s1 = csr[j + 2], s2 = csr[j + 4], s3 = csr[j + 6];
    float v0 = bf2f(XMLV[(size_t)s0 * 32 + c]);
    float v1 = bf2f(XMLV[(size_t)s1 * 32 + c]);
    float v2 = bf2f(XMLV[(size_t)s2 * 32 + c]);
    float v3 = bf2f(XMLV[(size_t)s3 * 32 + c]);
    s += v0; s += v1; s += v2; s += v3;
  }
  for (; j < end; j += 2) s += bf2f(XMLV[(size_t)csr[j] * 32 + c]);
  s += __shfl(s, lane ^ 32, 64);
  if (half == 0) {
    s *= in_is[g];
    float other = __shfl(s, lane ^ 16, 64);  // mu lane c gets logvar from lane c+16
    if (c < 16) {
      uint32_t i = (uint32_t)(g * NCLS + c);
      uint32_t bits = tf_bits32(ke0, ke1, i);
      float f = __uint_as_float((bits >> 9) | 0x3f800000u) - 1.0f;
      const float lo = -0.99999994f;          // nextafter(-1,0)
      float u = fmaxf(lo, fmaf(f, 2.0f, lo)); // (hi-lo) rounds to exactly 2.0f
      float eps = 1.41421356f * erfinv_f32(u);
      out[i] = eps * expf(other) + s;
    }
  }
}

// ---------------- host ----------------
extern "C" void kernel_launch(void* const* d_in, const int* in_sizes, int n_in,
                              void* d_out, int out_size, void* d_ws, size_t ws_size,
                              hipStream_t stream) {
  (void)in_sizes; (void)n_in; (void)out_size; (void)ws_size;
  const float* x  = (const float*)d_in[0];
  const float* W1 = (const float*)d_in[1];
  const float* W2 = (const float*)d_in[2];
  const float* W3 = (const float*)d_in[3];
  const int* esrc = (const int*)d_in[4];
  const int* edst = (const int*)d_in[5];
  float* out = (float*)d_out;

  // subkeys of jax.random.split(jax.random.key(42), 4):
  // partitionable split -> key_i = FULL threefry output pair at counter (hi=0, lo=i)
  uint32_t kb[8];
  for (int j = 0; j < 4; ++j)
    threefry2x32(0u, 42u, 0u, (uint32_t)j, kb[2 * j], kb[2 * j + 1]);
  // k1=(kb0,kb1) drop-x; k2a=(kb2,kb3); k2b=(kb4,kb5); keps=(kb6,kb7)

  // workspace carve
  char* p = (char*)d_ws;
  auto take = [&](size_t bytes) -> void* {
    void* r = (void*)p;
    p += (bytes + 255) & ~(size_t)255;
    return r;
  };
  u16* Xb        = (u16*)take(sizeof(u16) * (size_t)N_NODES * IN_DIM);
  u16* X1b       = (u16*)take(sizeof(u16) * (size_t)N_NODES * HID);
  u16* h1b       = (u16*)take(sizeof(u16) * (size_t)N_NODES * HID);
  u16* XMLV      = (u16*)take(sizeof(u16) * (size_t)N_NODES * 32);
  u16* W1t       = (u16*)take(sizeof(u16) * (size_t)IN_DIM * HID);
  u16* Wt23      = (u16*)take(sizeof(u16) * 32 * HID);
  uint32_t* mask2a = (uint32_t*)take((size_t)N_NODES * HID / 8);
  uint32_t* mask2b = (uint32_t*)take((size_t)N_NODES * HID / 8);
  int* out_deg   = (int*)take(sizeof(int) * N_NODES);
  int* in_deg    = (int*)take(sizeof(int) * N_NODES);
  float* out_is  = (float*)take(sizeof(float) * N_NODES);
  float* in_is   = (float*)take(sizeof(float) * N_NODES);
  int* row_ofs   = (int*)take(sizeof(int) * (N_NODES + 1));
  int* cursor    = (int*)take(sizeof(int) * N_NODES);
  int* csr       = (int*)take(sizeof(int) * N_EDGES);
  float* bn      = (float*)take(sizeof(float) * 1024);

  hipMemsetAsync(out_deg, 0, sizeof(int) * N_NODES, stream);
  hipMemsetAsync(in_deg, 0, sizeof(int) * N_NODES, stream);
  hipMemsetAsync(bn, 0, sizeof(float) * 512, stream);

  degrees_k<<<N_EDGES / 256, 256, 0, stream>>>(esrc, edst, out_deg, in_deg);
  invsqrt_k<<<(N_NODES + 255) / 256, 256, 0, stream>>>(out_deg, in_deg, out_is, in_is);
  scan_offsets_k<<<1, 1024, 0, stream>>>(in_deg, row_ofs, cursor);
  for (int w = 0; w < NPASS; ++w)
    scatter_win_k<<<N_EDGES / 256, 256, 0, stream>>>(esrc, edst, cursor, csr, w * WINSZ);

  gen_mask_k<<<(N_NODES * HID) / 256, 256, 0, stream>>>(kb[2], kb[3], mask2a);
  gen_mask_k<<<(N_NODES * HID) / 256, 256, 0, stream>>>(kb[4], kb[5], mask2b);

  cast_w1_k<<<(IN_DIM * HID) / 256, 256, 0, stream>>>(W1, W1t);
  cast_w23_k<<<(32 * HID) / 256, 256, 0, stream>>>(W2, W3, Wt23);
  cast_x_k<<<(N_NODES * IN_DIM / 8) / 256, 256, 0, stream>>>(x, out_is, kb[0], kb[1], Xb);

  gemm1_k<<<(N_NODES + 63) / 64, 256, 0, stream>>>(Xb, W1t, X1b);
  agg_relu_k<<<N_NODES / 4, 256, 0, stream>>>(X1b, row_ofs, csr, in_is, h1b);
  bn_stats_k<<<512, 256, 0, stream>>>(h1b, bn);
  bn_fin_k<<<1, 256, 0, stream>>>(bn);
  gemm23_k<<<(N_NODES + 63) / 64, 256, 0, stream>>>(h1b, Wt23, mask2a, mask2b, out_is, bn, XMLV);
  agg_final_k<<<N_NODES / 4, 256, 0, stream>>>(XMLV, row_ofs, csr, in_is, kb[6], kb[7], out);
}

// Round 7
// 1294.562 us; speedup vs baseline: 1.7427x; 1.1898x over previous
//
#include <hip/hip_runtime.h>
#include <stdint.h>

#define N_NODES 100000
#define N_EDGES 3200000
#define IN_DIM  512
#define HID     256
#define NCLS    16

// graph-prep histogram geometry
#define DBLK   256                   // blocks (one per CU)
#define DCHUNK (N_EDGES / DBLK)      // 12500 edges per block
#define DWIN   25000                 // nodes per LDS window (100 KB)
#define DNWIN  (N_NODES / DWIN)      // 4 windows

typedef unsigned short u16;
typedef __attribute__((ext_vector_type(8))) short short8;
typedef __attribute__((ext_vector_type(4))) float float4v;

// ---------------- bf16 helpers ----------------
__device__ __forceinline__ float bf2f(u16 u) {
  return __uint_as_float(((uint32_t)u) << 16);
}
__device__ __forceinline__ u16 f2bf(float f) {   // round-to-nearest-even
  uint32_t u = __float_as_uint(f);
  return (u16)((u + 0x7fffu + ((u >> 16) & 1u)) >> 16);
}
__device__ __forceinline__ void acc8(float* a, uint4 v) {
  a[0] += bf2f((u16)(v.x & 0xffffu)); a[1] += bf2f((u16)(v.x >> 16));
  a[2] += bf2f((u16)(v.y & 0xffffu)); a[3] += bf2f((u16)(v.y >> 16));
  a[4] += bf2f((u16)(v.z & 0xffffu)); a[5] += bf2f((u16)(v.z >> 16));
  a[6] += bf2f((u16)(v.w & 0xffffu)); a[7] += bf2f((u16)(v.w >> 16));
}

// ---------------- Threefry-2x32 (exact JAX schedule, partitionable mode) ----------------
__host__ __device__ __forceinline__ uint32_t rotl32(uint32_t v, int d) {
  return (v << d) | (v >> (32 - d));
}

__host__ __device__ __forceinline__ void threefry2x32(uint32_t k0, uint32_t k1,
    uint32_t x0, uint32_t x1, uint32_t& o0, uint32_t& o1) {
  uint32_t ks0 = k0, ks1 = k1, ks2 = k0 ^ k1 ^ 0x1BD11BDAu;
  x0 += ks0; x1 += ks1;
#define TF_R(r) { x0 += x1; x1 = rotl32(x1, r); x1 ^= x0; }
  TF_R(13) TF_R(15) TF_R(26) TF_R(6)
  x0 += ks1; x1 += ks2 + 1u;
  TF_R(17) TF_R(29) TF_R(16) TF_R(24)
  x0 += ks2; x1 += ks0 + 2u;
  TF_R(13) TF_R(15) TF_R(26) TF_R(6)
  x0 += ks0; x1 += ks1 + 3u;
  TF_R(17) TF_R(29) TF_R(16) TF_R(24)
  x0 += ks1; x1 += ks2 + 4u;
  TF_R(13) TF_R(15) TF_R(26) TF_R(6)
  x0 += ks2; x1 += ks0 + 5u;
#undef TF_R
  o0 = x0; o1 = x1;
}

__host__ __device__ __forceinline__ uint32_t tf_bits32(uint32_t k0, uint32_t k1, uint32_t idx) {
  uint32_t o0, o1;
  threefry2x32(k0, k1, 0u, idx, o0, o1);
  return o0 ^ o1;
}

// ---------------- erfinv: XLA/Giles f32 polynomial ----------------
__device__ __forceinline__ float erfinv_f32(float x) {
  float w = -log1pf(-x * x);
  float p;
  if (w < 5.0f) {
    w -= 2.5f;
    p = 2.81022636e-08f;
    p = fmaf(p, w, 3.43273939e-07f);
    p = fmaf(p, w, -3.5233877e-06f);
    p = fmaf(p, w, -4.39150654e-06f);
    p = fmaf(p, w, 0.00021858087f);
    p = fmaf(p, w, -0.00125372503f);
    p = fmaf(p, w, -0.00417768164f);
    p = fmaf(p, w, 0.246640727f);
    p = fmaf(p, w, 1.50140941f);
  } else {
    w = sqrtf(w) - 3.0f;
    p = -0.000200214257f;
    p = fmaf(p, w, 0.000100950558f);
    p = fmaf(p, w, 0.00134934322f);
    p = fmaf(p, w, -0.00367342844f);
    p = fmaf(p, w, 0.00573950773f);
    p = fmaf(p, w, -0.0076224613f);
    p = fmaf(p, w, 0.00943887047f);
    p = fmaf(p, w, 1.00167406f);
    p = fmaf(p, w, 2.83297682f);
  }
  return p * x;
}

// ---------------- graph prep: privatized histogram, no global atomics ----------------
// P[b][node] u32: lo16 = out-count, hi16 = in-count of block b's edge chunk.
__global__ __launch_bounds__(256) void hist_k(
    const int* __restrict__ esrc, const int* __restrict__ edst,
    uint32_t* __restrict__ P) {
  __shared__ uint32_t hist[DWIN];
  const int b = blockIdx.x, tid = threadIdx.x;
  const int ebase = b * DCHUNK;
  for (int w = 0; w < DNWIN; ++w) {
    const int lo = w * DWIN;
    for (int i = tid; i < DWIN; i += 256) hist[i] = 0u;
    __syncthreads();
    for (int e = ebase + tid; e < ebase + DCHUNK; e += 256) {
      int s = esrc[e], d = edst[e];
      if ((unsigned)(s - lo) < (unsigned)DWIN) atomicAdd(&hist[s - lo], 1u);
      if ((unsigned)(d - lo) < (unsigned)DWIN) atomicAdd(&hist[d - lo], 0x10000u);
    }
    __syncthreads();
    for (int i = tid; i < DWIN; i += 256)
      P[(size_t)b * N_NODES + lo + i] = hist[i];
    __syncthreads();
  }
}

// column-sum partials -> degrees; rewrite P[b][n] with exclusive in-prefix over blocks
__global__ void degsum_k(uint32_t* __restrict__ P,
                         int* __restrict__ outd, int* __restrict__ ind) {
  int n = blockIdx.x * 256 + threadIdx.x;
  if (n >= N_NODES) return;
  uint32_t to = 0, ti = 0;
  for (int b = 0; b < DBLK; ++b) {
    uint32_t v = P[(size_t)b * N_NODES + n];
    P[(size_t)b * N_NODES + n] = ti;      // in-prefix: CSR slot base for (b, n)
    to += v & 0xffffu; ti += v >> 16;
  }
  outd[n] = (int)to; ind[n] = (int)ti;
}

__global__ void invsqrt_k(const int* __restrict__ outd, const int* __restrict__ ind,
                          float* __restrict__ out_is, float* __restrict__ in_is) {
  int i = blockIdx.x * blockDim.x + threadIdx.x;
  if (i < N_NODES) {
    out_is[i] = rsqrtf(fmaxf((float)outd[i], 1.0f));
    in_is[i]  = rsqrtf(fmaxf((float)ind[i], 1.0f));
  }
}

__global__ void scan_offsets_k(const int* __restrict__ ind, int* __restrict__ row_ofs) {
  __shared__ int part[1024];
  const int tid = threadIdx.x;
  const int chunk = (N_NODES + 1023) / 1024;
  int s0 = tid * chunk;
  int s1 = s0 + chunk; if (s1 > N_NODES) s1 = N_NODES; if (s0 > N_NODES) s0 = N_NODES;
  int sum = 0;
  for (int i = s0; i < s1; ++i) sum += ind[i];
  part[tid] = sum;
  __syncthreads();
  for (int d = 1; d < 1024; d <<= 1) {
    int v = (tid >= d) ? part[tid - d] : 0;
    __syncthreads();
    part[tid] += v;
    __syncthreads();
  }
  int run = part[tid] - sum;  // exclusive prefix of this chunk
  for (int i = s0; i < s1; ++i) {
    row_ofs[i] = run;
    run += ind[i];
  }
  if (tid == 1023) row_ofs[N_NODES] = part[1023];
}

// atomic-free CSR placement: block b places its chunk at row_ofs[n] + P[b][n] + lds-cursor
__global__ __launch_bounds__(256) void place_k(
    const int* __restrict__ esrc, const int* __restrict__ edst,
    const uint32_t* __restrict__ P, const int* __restrict__ row_ofs,
    int* __restrict__ csr) {
  __shared__ int cur[DWIN];
  const int b = blockIdx.x, tid = threadIdx.x;
  const int ebase = b * DCHUNK;
  for (int w = 0; w < DNWIN; ++w) {
    const int lo = w * DWIN;
    for (int i = tid; i < DWIN; i += 256)
      cur[i] = row_ofs[lo + i] + (int)P[(size_t)b * N_NODES + lo + i];
    __syncthreads();
    for (int e = ebase + tid; e < ebase + DCHUNK; e += 256) {
      int d = edst[e];
      if ((unsigned)(d - lo) < (unsigned)DWIN) {
        int p = atomicAdd(&cur[d - lo], 1);   // LDS atomic (CU-local)
        csr[p] = esrc[e];
      }
    }
    __syncthreads();
  }
}

// ---------------- dropout mask bits for hidden layer (1 bit per element) ----------------
__global__ void gen_mask_k(uint32_t k0, uint32_t k1, uint32_t* __restrict__ mask) {
  uint32_t idx = blockIdx.x * blockDim.x + threadIdx.x;   // exact grid = size
  uint32_t bits = tf_bits32(k0, k1, idx);
  unsigned long long bal = __ballot((bits >> 31) == 0u);  // keep := u < 0.5
  if ((threadIdx.x & 63) == 0) {
    uint32_t w = idx >> 5;
    mask[w] = (uint32_t)bal;
    mask[w + 1] = (uint32_t)(bal >> 32);
  }
}

// ---------------- Xb = bf16(dropout1(x) * 2 * out_is) ----------------
__global__ __launch_bounds__(256) void cast_x_k(
    const float* __restrict__ x, const float* __restrict__ out_is,
    uint32_t k0, uint32_t k1, u16* __restrict__ Xb) {
  uint32_t t = blockIdx.x * 256u + threadIdx.x;   // 6.4M threads, 8 elems each
  uint32_t idx = t * 8u;
  uint32_t row = idx >> 9;
  float sc = 2.0f * out_is[row];
  float4 v0 = *(const float4*)(x + idx);
  float4 v1 = *(const float4*)(x + idx + 4);
  float vv[8] = {v0.x, v0.y, v0.z, v0.w, v1.x, v1.y, v1.z, v1.w};
  u16 o[8];
#pragma unroll
  for (int j = 0; j < 8; ++j) {
    uint32_t bits = tf_bits32(k0, k1, idx + (uint32_t)j);
    float val = (bits >> 31) ? 0.0f : vv[j] * sc;
    o[j] = f2bf(val);
  }
  uint4 pk;
  pk.x = (uint32_t)o[0] | ((uint32_t)o[1] << 16);
  pk.y = (uint32_t)o[2] | ((uint32_t)o[3] << 16);
  pk.z = (uint32_t)o[4] | ((uint32_t)o[5] << 16);
  pk.w = (uint32_t)o[6] | ((uint32_t)o[7] << 16);
  *(uint4*)(Xb + idx) = pk;
}

// ---------------- W1t = bf16(W1^T)  [256][512] ----------------
__global__ void cast_w1_k(const float* __restrict__ W1, u16* __restrict__ W1t) {
  int idx = blockIdx.x * blockDim.x + threadIdx.x;   // exact grid = 512*256
  int k = idx >> 8, n = idx & 255;
  W1t[n * IN_DIM + k] = f2bf(W1[idx]);
}

// ---------------- Wt23 = bf16([W2^T ; W3^T])  [32][256] ----------------
__global__ void cast_w23_k(const float* __restrict__ W2, const float* __restrict__ W3,
                           u16* __restrict__ Wt23) {
  int idx = blockIdx.x * blockDim.x + threadIdx.x;   // exact grid = 32*256
  int n = idx >> 8, k = idx & 255;
  float v = (n < 16) ? W2[k * NCLS + n] : W3[k * NCLS + (n - 16)];
  Wt23[n * HID + k] = f2bf(v);
}

// ---------------- GEMM1 (MFMA bf16): X1b = Xb @ W1  [100000,512]x[512,256] -> bf16 ----------------
#define LDA 40   // ushort stride (80 B: 16B-aligned rows, dword-stride 20 -> <=2-way bank alias)
__global__ __launch_bounds__(256) void gemm1_k(
    const u16* __restrict__ Xb, const u16* __restrict__ W1t, u16* __restrict__ X1b) {
  __shared__ u16 As[64 * LDA];    // [row][k0..31]
  __shared__ u16 Bs[256 * LDA];   // [n][k0..31]
  const int tid = threadIdx.x;
  const int w = tid >> 6, l = tid & 63;
  const int m16 = l & 15, q = l >> 4;
  const long base_row = (long)blockIdx.x * 64;

  float4v acc[4][4];
#pragma unroll
  for (int i = 0; i < 4; ++i)
#pragma unroll
    for (int j = 0; j < 4; ++j) acc[i][j] = (float4v)0.0f;

  const int arow = tid >> 2, ac = tid & 3;   // A staging: 64 rows x 4 chunks(8 bf16)
  const long agr = base_row + arow;

  for (int k0 = 0; k0 < IN_DIM; k0 += 32) {
    uint4 va = make_uint4(0, 0, 0, 0);
    if (agr < N_NODES) va = *(const uint4*)(Xb + agr * IN_DIM + k0 + ac * 8);
    *(uint4*)(As + arow * LDA + ac * 8) = va;
#pragma unroll
    for (int c = 0; c < 4; ++c) {   // B staging: n = tid, 32 bf16 per row (L2-resident W1t)
      uint4 vb = *(const uint4*)(W1t + (size_t)tid * IN_DIM + k0 + c * 8);
      *(uint4*)(Bs + tid * LDA + c * 8) = vb;
    }
    __syncthreads();
    short8 a[4], b[4];
#pragma unroll
    for (int rt = 0; rt < 4; ++rt)
      a[rt] = *(const short8*)(As + (rt * 16 + m16) * LDA + q * 8);
#pragma unroll
    for (int ct = 0; ct < 4; ++ct)
      b[ct] = *(const short8*)(Bs + ((w * 4 + ct) * 16 + m16) * LDA + q * 8);
#pragma unroll
    for (int rt = 0; rt < 4; ++rt)
#pragma unroll
      for (int ct = 0; ct < 4; ++ct)
        acc[rt][ct] = __builtin_amdgcn_mfma_f32_16x16x32_bf16(a[rt], b[ct], acc[rt][ct], 0, 0, 0);
    __syncthreads();
  }
#pragma unroll
  for (int rt = 0; rt < 4; ++rt) {
#pragma unroll
    for (int r = 0; r < 4; ++r) {
      long grow = base_row + rt * 16 + q * 4 + r;
      if (grow < N_NODES) {
#pragma unroll
        for (int ct = 0; ct < 4; ++ct)
          X1b[grow * HID + (w * 4 + ct) * 16 + m16] = f2bf(acc[rt][ct][r]);
      }
    }
  }
}

// ---------------- CSR gather-sum (bf16) + relu -> h1 bf16 ----------------
__global__ __launch_bounds__(256) void agg_relu_k(
    const u16* __restrict__ X1b, const int* __restrict__ row_ofs,
    const int* __restrict__ csr, const float* __restrict__ in_is,
    u16* __restrict__ h1b) {
  int d = blockIdx.x * 4 + (threadIdx.x >> 6);  // exact: 25000*4 = N
  int lane = threadIdx.x & 63;
  int half = lane >> 5;
  int col = (lane & 31) * 8;
  int beg = row_ofs[d], end = row_ofs[d + 1];
  float a[8];
#pragma unroll
  for (int i = 0; i < 8; ++i) a[i] = 0.0f;
  int j = beg + half;
  for (; j + 6 < end; j += 8) {
    int s0 = csr[j], s1 = csr[j + 2], s2 = csr[j + 4], s3 = csr[j + 6];
    uint4 v0 = *(const uint4*)(X1b + (size_t)s0 * HID + col);
    uint4 v1 = *(const uint4*)(X1b + (size_t)s1 * HID + col);
    uint4 v2 = *(const uint4*)(X1b + (size_t)s2 * HID + col);
    uint4 v3 = *(const uint4*)(X1b + (size_t)s3 * HID + col);
    acc8(a, v0); acc8(a, v1); acc8(a, v2); acc8(a, v3);
  }
  for (; j < end; j += 2) {
    uint4 v0 = *(const uint4*)(X1b + (size_t)csr[j] * HID + col);
    acc8(a, v0);
  }
#pragma unroll
  for (int i = 0; i < 8; ++i) a[i] += __shfl(a[i], lane ^ 32, 64);
  if (half == 0) {
    float is = in_is[d];
    u16 o[8];
#pragma unroll
    for (int i = 0; i < 8; ++i) o[i] = f2bf(fmaxf(a[i] * is, 0.0f));
    uint4 pk;
    pk.x = (uint32_t)o[0] | ((uint32_t)o[1] << 16);
    pk.y = (uint32_t)o[2] | ((uint32_t)o[3] << 16);
    pk.z = (uint32_t)o[4] | ((uint32_t)o[5] << 16);
    pk.w = (uint32_t)o[6] | ((uint32_t)o[7] << 16);
    *(uint4*)(h1b + (size_t)d * HID + col) = pk;
  }
}

// ---------------- BatchNorm stats (bf16 in, fp32 accumulate) ----------------
__global__ void bn_stats_k(const u16* __restrict__ h1b, float* __restrict__ bn) {
  int c = threadIdx.x;  // 256 threads
  float s = 0.f, s2 = 0.f;
  for (int r = blockIdx.x; r < N_NODES; r += gridDim.x) {
    float v = bf2f(h1b[(size_t)r * HID + c]);
    s += v; s2 += v * v;
  }
  atomicAdd(&bn[c], s);
  atomicAdd(&bn[HID + c], s2);
}

__global__ void bn_fin_k(float* __restrict__ bn) {
  int c = threadIdx.x;
  float mean = bn[c] / (float)N_NODES;
  float var = bn[HID + c] / (float)N_NODES - mean * mean;
  float istd = rsqrtf(var + 1e-5f);
  bn[512 + c] = istd;           // cB
  bn[768 + c] = -mean * istd;   // cA:  normalized = h*cB + cA
}

// ---------------- GEMM2/3 (MFMA): XMLV[row] = [mu(16) | logvar(16)] bf16 ----------------
#define WLS 264   // u16 row stride for Wls: dword-stride 132 -> 2-way bank alias (free)
__global__ __launch_bounds__(256) void gemm23_k(
    const u16* __restrict__ h1b, const u16* __restrict__ Wt23,
    const uint32_t* __restrict__ mask2a, const uint32_t* __restrict__ mask2b,
    const float* __restrict__ out_is, const float* __restrict__ bn,
    u16* __restrict__ XMLV) {
  __shared__ u16 Wls[32 * WLS];
  __shared__ float cB[HID], cA[HID];
  const int tid = threadIdx.x;
#pragma unroll
  for (int i = 0; i < 4; ++i) {   // stage Wt23 (16KB) into padded LDS
    int idx = tid + i * 256;      // 1024 uint4 chunks
    int n = idx >> 5, c = idx & 31;
    *(uint4*)(Wls + n * WLS + c * 8) = ((const uint4*)Wt23)[idx];
  }
  cB[tid] = bn[512 + tid];
  cA[tid] = bn[768 + tid];
  __syncthreads();

  const int wv = tid >> 6, lane = tid & 63;
  const int m = lane & 15, q = lane >> 4;
  const long arow = (long)blockIdx.x * 64 + wv * 16 + m;   // A row this lane loads
  const bool valid = arow < N_NODES;
  const float osc = valid ? 2.0f * out_is[arow] : 0.0f;

  float4v accM = (float4v)0.0f, accL = (float4v)0.0f;
  for (int kc = 0; kc < HID; kc += 32) {
    const int kof = kc + q * 8;
    uint4 hv = make_uint4(0, 0, 0, 0);
    uint32_t wa = 0, wb = 0;
    if (valid) {
      hv = *(const uint4*)(h1b + arow * HID + kof);
      uint32_t widx = ((uint32_t)arow * HID + (uint32_t)kc) >> 5;
      wa = mask2a[widx] >> (q * 8);
      wb = mask2b[widx] >> (q * 8);
    }
    float4 B0 = *(const float4*)(cB + kof);
    float4 B1 = *(const float4*)(cB + kof + 4);
    float4 A0 = *(const float4*)(cA + kof);
    float4 A1 = *(const float4*)(cA + kof + 4);
    float hval[8] = {
      bf2f((u16)(hv.x & 0xffffu)), bf2f((u16)(hv.x >> 16)),
      bf2f((u16)(hv.y & 0xffffu)), bf2f((u16)(hv.y >> 16)),
      bf2f((u16)(hv.z & 0xffffu)), bf2f((u16)(hv.z >> 16)),
      bf2f((u16)(hv.w & 0xffffu)), bf2f((u16)(hv.w >> 16))};
    float nb[8] = {B0.x, B0.y, B0.z, B0.w, B1.x, B1.y, B1.z, B1.w};
    float na[8] = {A0.x, A0.y, A0.z, A0.w, A1.x, A1.y, A1.z, A1.w};
    short8 Aa, Ab;
#pragma unroll
    for (int jj = 0; jj < 8; ++jj) {
      float t = fmaf(hval[jj], nb[jj], na[jj]) * osc;
      u16 tb = f2bf(t);
      Aa[jj] = (short)(((wa >> jj) & 1u) ? tb : 0);
      Ab[jj] = (short)(((wb >> jj) & 1u) ? tb : 0);
    }
    short8 Bm = *(const short8*)(Wls + m * WLS + kof);          // W2 col m
    short8 Bl = *(const short8*)(Wls + (16 + m) * WLS + kof);   // W3 col m
    accM = __builtin_amdgcn_mfma_f32_16x16x32_bf16(Aa, Bm, accM, 0, 0, 0);
    accL = __builtin_amdgcn_mfma_f32_16x16x32_bf16(Ab, Bl, accL, 0, 0, 0);
  }
  // D: row = q*4+r, col = m
#pragma unroll
  for (int r = 0; r < 4; ++r) {
    long srow = (long)blockIdx.x * 64 + wv * 16 + q * 4 + r;
    if (srow < N_NODES) {
      XMLV[srow * 32 + m]      = f2bf(accM[r]);
      XMLV[srow * 32 + 16 + m] = f2bf(accL[r]);
    }
  }
}

// ---------------- final: aggregate interleaved mu|logvar + reparameterize ----------------
__global__ __launch_bounds__(256) void agg_final_k(
    const u16* __restrict__ XMLV, const int* __restrict__ row_ofs,
    const int* __restrict__ csr, const float* __restrict__ in_is,
    uint32_t ke0, uint32_t ke1, float* __restrict__ out) {
  int g = blockIdx.x * 4 + (threadIdx.x >> 6);  // exact: 25000*4 = N
  int lane = threadIdx.x & 63;
  int half = lane >> 5, c = lane & 31;
  int beg = row_ofs[g], end = row_ofs[g + 1];
  float s = 0.f;
  int j = beg + half;
  for (; j + 6 < end; j += 8) {
    int s0 = csr[j], s1 = csr[j + 2], s2 = csr[j + 4], s3 = csr[j + 6];
    float v0 = bf2f(XMLV[(size_t)s0 * 32 + c]);
    float v1 = bf2f(XMLV[(size_t)s1 * 32 + c]);
    float v2 = bf2f(XMLV[(size_t)s2 * 32 + c]);
    float v3 = bf2f(XMLV[(size_t)s3 * 32 + c]);
    s += v0; s += v1; s += v2; s += v3;
  }
  for (; j < end; j += 2) s += bf2f(XMLV[(size_t)csr[j] * 32 + c]);
  s += __shfl(s, lane ^ 32, 64);
  if (half == 0) {
    s *= in_is[g];
    float other = __shfl(s, lane ^ 16, 64);  // mu lane c gets logvar from lane c+16
    if (c < 16) {
      uint32_t i = (uint32_t)(g * NCLS + c);
      uint32_t bits = tf_bits32(ke0, ke1, i);
      float f = __uint_as_float((bits >> 9) | 0x3f800000u) - 1.0f;
      const float lo = -0.99999994f;          // nextafter(-1,0)
      float u = fmaxf(lo, fmaf(f, 2.0f, lo)); // (hi-lo) rounds to exactly 2.0f
      float eps = 1.41421356f * erfinv_f32(u);
      out[i] = eps * expf(other) + s;
    }
  }
}

// ---------------- host ----------------
extern "C" void kernel_launch(void* const* d_in, const int* in_sizes, int n_in,
                              void* d_out, int out_size, void* d_ws, size_t ws_size,
                              hipStream_t stream) {
  (void)in_sizes; (void)n_in; (void)out_size; (void)ws_size;
  const float* x  = (const float*)d_in[0];
  const float* W1 = (const float*)d_in[1];
  const float* W2 = (const float*)d_in[2];
  const float* W3 = (const float*)d_in[3];
  const int* esrc = (const int*)d_in[4];
  const int* edst = (const int*)d_in[5];
  float* out = (float*)d_out;

  // subkeys of jax.random.split(jax.random.key(42), 4):
  // partitionable split -> key_i = FULL threefry output pair at counter (hi=0, lo=i)
  uint32_t kb[8];
  for (int j = 0; j < 4; ++j)
    threefry2x32(0u, 42u, 0u, (uint32_t)j, kb[2 * j], kb[2 * j + 1]);
  // k1=(kb0,kb1) drop-x; k2a=(kb2,kb3); k2b=(kb4,kb5); keps=(kb6,kb7)

  // workspace carve
  char* p = (char*)d_ws;
  auto take = [&](size_t bytes) -> void* {
    void* r = (void*)p;
    p += (bytes + 255) & ~(size_t)255;
    return r;
  };
  u16* Xb        = (u16*)take(sizeof(u16) * (size_t)N_NODES * IN_DIM);   // 102.4 MB
  u16* X1b       = (u16*)take(sizeof(u16) * (size_t)N_NODES * HID);
  u16* h1b       = (u16*)take(sizeof(u16) * (size_t)N_NODES * HID);
  u16* XMLV      = (u16*)take(sizeof(u16) * (size_t)N_NODES * 32);
  u16* W1t       = (u16*)take(sizeof(u16) * (size_t)IN_DIM * HID);
  u16* Wt23      = (u16*)take(sizeof(u16) * 32 * HID);
  uint32_t* mask2a = (uint32_t*)take((size_t)N_NODES * HID / 8);
  uint32_t* mask2b = (uint32_t*)take((size_t)N_NODES * HID / 8);
  int* out_deg   = (int*)take(sizeof(int) * N_NODES);
  int* in_deg    = (int*)take(sizeof(int) * N_NODES);
  float* out_is  = (float*)take(sizeof(float) * N_NODES);
  float* in_is   = (float*)take(sizeof(float) * N_NODES);
  int* row_ofs   = (int*)take(sizeof(int) * (N_NODES + 1));
  int* csr       = (int*)take(sizeof(int) * N_EDGES);
  float* bn      = (float*)take(sizeof(float) * 1024);

  // P partials [DBLK][N_NODES] u32 = 102.4 MB, aliased onto Xb (consumed before cast_x)
  uint32_t* P = (uint32_t*)Xb;

  hipMemsetAsync(bn, 0, sizeof(float) * 512, stream);

  hist_k<<<DBLK, 256, 0, stream>>>(esrc, edst, P);
  degsum_k<<<(N_NODES + 255) / 256, 256, 0, stream>>>(P, out_deg, in_deg);
  invsqrt_k<<<(N_NODES + 255) / 256, 256, 0, stream>>>(out_deg, in_deg, out_is, in_is);
  scan_offsets_k<<<1, 1024, 0, stream>>>(in_deg, row_ofs);
  place_k<<<DBLK, 256, 0, stream>>>(esrc, edst, P, row_ofs, csr);

  gen_mask_k<<<(N_NODES * HID) / 256, 256, 0, stream>>>(kb[2], kb[3], mask2a);
  gen_mask_k<<<(N_NODES * HID) / 256, 256, 0, stream>>>(kb[4], kb[5], mask2b);

  cast_w1_k<<<(IN_DIM * HID) / 256, 256, 0, stream>>>(W1, W1t);
  cast_w23_k<<<(32 * HID) / 256, 256, 0, stream>>>(W2, W3, Wt23);
  cast_x_k<<<(N_NODES * IN_DIM / 8) / 256, 256, 0, stream>>>(x, out_is, kb[0], kb[1], Xb);

  gemm1_k<<<(N_NODES + 63) / 64, 256, 0, stream>>>(Xb, W1t, X1b);
  agg_relu_k<<<N_NODES / 4, 256, 0, stream>>>(X1b, row_ofs, csr, in_is, h1b);
  bn_stats_k<<<512, 256, 0, stream>>>(h1b, bn);
  bn_fin_k<<<1, 256, 0, stream>>>(bn);
  gemm23_k<<<(N_NODES + 63) / 64, 256, 0, stream>>>(h1b, Wt23, mask2a, mask2b, out_is, bn, XMLV);
  agg_final_k<<<N_NODES / 4, 256, 0, stream>>>(XMLV, row_ofs, csr, in_is, kb[6], kb[7], out);
}